// Round 4
// baseline (1363.290 us; speedup 1.0000x reference)
//
#include <hip/hip_runtime.h>
#include <hip/hip_bf16.h>

typedef __bf16 bf16x8 __attribute__((ext_vector_type(8)));
typedef float f32x4 __attribute__((ext_vector_type(4)));
typedef float f32x4v __attribute__((ext_vector_type(4)));
typedef unsigned short u16x8 __attribute__((ext_vector_type(8)));
typedef unsigned short u16x4 __attribute__((ext_vector_type(4)));

#define NHEADS 12
#define SCALE 0.05103103630798288f  /* 384^-0.5 */
#define MFMA __builtin_amdgcn_mfma_f32_16x16x32_bf16

static __device__ __forceinline__ unsigned short f2b(float f){
    unsigned u = __float_as_uint(f);
    unsigned r = u + 0x7FFFu + ((u >> 16) & 1u);
    return (unsigned short)(r >> 16);
}
static __device__ __forceinline__ float b2f(unsigned short u){
    union { float f; unsigned u32; } v; v.u32 = ((unsigned)u) << 16; return v.f;
}

// q/k/v global layout (per head-pair, 2048 u16): granule-permuted so BOTH the
// qkv stores (512B contiguous per instruction) and the attn fragment loads
// (16B/lane) are fully coalesced:
//   q/k (element (tok,d)):  off = (d>>4)*1024 + (tok>>4)*256 + ((d>>3)&1)*128
//                                 + (tok&15)*8 + ((d>>2)&1)*4
//   v   (element (d,tok)):  off = (d>>4)*1024 + (tok>>4)*256 + ((tok>>3)&1)*128
//                                 + (d&15)*8 + ((tok>>2)&1)*4

// ---------------------------------------------------------------- prep (FULL)
__global__ void prep_full(const float* __restrict__ wqkv, const float* __restrict__ wproj,
                          const float* __restrict__ emb, const int* __restrict__ indices,
                          const float* __restrict__ mask,
                          unsigned short* __restrict__ wqkvP,
                          unsigned short* __restrict__ wprojP,
                          unsigned short* __restrict__ bm2){
    int i = blockIdx.x * 256 + threadIdx.x;
    if (i < 442368){
        int j = i & 7, rest = i >> 3;
        int ln = rest & 63; rest >>= 6;
        int kf = rest % 12, t = rest / 12;
        int k = kf * 32 + (ln >> 4) * 8 + j;
        int col = t * 16 + (ln & 15);
        wqkvP[i] = f2b(wqkv[k * 1152 + col]);
        return;
    }
    i -= 442368;
    if (i < 147456){
        int j = i & 7, rest = i >> 3;
        int ln = rest & 63; rest >>= 6;
        int kf = rest % 12, t = rest / 12;
        int k = kf * 32 + (ln >> 4) * 8 + j;
        int col = t * 16 + (ln & 15);
        wprojP[i] = f2b(wproj[k * 384 + col]);
        return;
    }
    i -= 147456;
    if (i < 64 * 12 * 4096){
        int w = i / 49152, rem = i % 49152;
        int h = rem / 4096, r2 = rem & 4095;
        int col = r2 >> 6, row = r2 & 63;          // col=key, row=query
        int ij = row * 64 + col;
        float v = emb[indices[ij] * 12 + h] + emb[indices[4096 + ij] * 12 + h]
                + mask[w * 4096 + ij];
        bm2[i] = f2b(v);
    }
}

// ---------------------------------------------------------------- K1 (FULL)
// One window per block, 4 waves. 3 sections (q,k,v); each wave owns 6 W-tiles
// per section -> per kf: 4 A ds_reads feed 24 MFMAs (was 1:2, now 1:6).
// q/k: operand-swapped MFMA (d on regs, tok on lanes); v: normal. All stores
// go to the granule-permuted layout -> every store is 512B contiguous NT.
__global__ __launch_bounds__(256, 3) void qkv_gemm(
    const float* __restrict__ x, const unsigned short* __restrict__ wqkvP,
    unsigned short* __restrict__ qg, unsigned short* __restrict__ kg,
    unsigned short* __restrict__ vg)
{
    __shared__ unsigned short As[64 * 384];       // 48 KiB, chunk-swizzled
    const int tid = threadIdx.x, wave = tid >> 6, lane = tid & 63;
    const int lo = lane & 15, hi = lane >> 4;
    const int win = blockIdx.x;
    const int widx = win & 63, wh = widx >> 3, ww = widx & 7, b = win >> 6;

    { // stage A: row = tid>>2, 12 chunks of 8 bf16 each (nt f32 loads)
        const int r = tid >> 2;
        const int ih = r >> 3, iw = r & 7;
        const int gh = (wh * 8 + ih + 4) & 63, gw = (ww * 8 + iw + 4) & 63;
        const float* src = x + ((size_t)(b * 4096 + gh * 64 + gw)) * 384;
        unsigned short* dst = As + r * 384;
        const int sw = r & 7;
        #pragma unroll
        for (int i = 0; i < 12; ++i){
            const int c = (tid & 3) + i * 4;
            f32x4v f0 = __builtin_nontemporal_load(
                reinterpret_cast<const f32x4v*>(src + c * 8));
            f32x4v f1 = __builtin_nontemporal_load(
                reinterpret_cast<const f32x4v*>(src + c * 8 + 4));
            union { bf16x8 v; unsigned short s[8]; } u;
            u.s[0]=f2b(f0[0]); u.s[1]=f2b(f0[1]); u.s[2]=f2b(f0[2]); u.s[3]=f2b(f0[3]);
            u.s[4]=f2b(f1[0]); u.s[5]=f2b(f1[1]); u.s[6]=f2b(f1[2]); u.s[7]=f2b(f1[3]);
            const int cs = (c & ~7) | ((c & 7) ^ sw);
            *reinterpret_cast<bf16x8*>(dst + cs * 8) = u.v;
        }
    }
    __syncthreads();

    #pragma unroll 1
    for (int sec = 0; sec < 3; ++sec){
        const int t0 = sec * 24 + wave * 6;        // first of 6 W-tiles
        const unsigned short* bp = wqkvP + (size_t)t0 * 12 * 512 + lane * 8;

        f32x4 acc[6][4];                           // [wtile][ttile]
        #pragma unroll
        for (int wt = 0; wt < 6; ++wt)
            #pragma unroll
            for (int tt = 0; tt < 4; ++tt) acc[wt][tt] = {0,0,0,0};

        #pragma unroll 1
        for (int kf = 0; kf < 12; ++kf){
            bf16x8 bw[6];
            #pragma unroll
            for (int wt = 0; wt < 6; ++wt)
                bw[wt] = *reinterpret_cast<const bf16x8*>(bp + (wt * 12 + kf) * 512);
            const int c = kf * 4 + hi;
            if (sec < 2){
                #pragma unroll
                for (int tt = 0; tt < 4; ++tt){
                    const int r = tt * 16 + lo;
                    const int cs = (c & ~7) | ((c & 7) ^ (r & 7));
                    bf16x8 af = *reinterpret_cast<const bf16x8*>(As + r * 384 + cs * 8);
                    #pragma unroll
                    for (int wt = 0; wt < 6; ++wt)
                        acc[wt][tt] = MFMA(bw[wt], af, acc[wt][tt], 0, 0, 0);
                }
            } else {
                #pragma unroll
                for (int tt = 0; tt < 4; ++tt){
                    const int r = tt * 16 + lo;
                    const int cs = (c & ~7) | ((c & 7) ^ (r & 7));
                    bf16x8 af = *reinterpret_cast<const bf16x8*>(As + r * 384 + cs * 8);
                    #pragma unroll
                    for (int wt = 0; wt < 6; ++wt)
                        acc[wt][tt] = MFMA(af, bw[wt], acc[wt][tt], 0, 0, 0);
                }
            }
        }

        // epilogue: permuted-layout 8B pieces; each (wt,tt) store op = 512B contig
        const float sc = (sec == 0) ? SCALE : 1.0f;
        unsigned short* basep = (sec == 0 ? qg : sec == 1 ? kg : vg);
        #pragma unroll
        for (int wt = 0; wt < 6; ++wt){
            const int hloc = wave * 3 + (wt >> 1);
            unsigned short* dst = basep + (size_t)(win * 12 + hloc) * 2048
                                + (wt & 1) * 1024 + (hi >> 1) * 128 + lo * 8 + (hi & 1) * 4;
            #pragma unroll
            for (int tt = 0; tt < 4; ++tt){
                u16x4 u;
                u[0] = f2b(acc[wt][tt][0] * sc); u[1] = f2b(acc[wt][tt][1] * sc);
                u[2] = f2b(acc[wt][tt][2] * sc); u[3] = f2b(acc[wt][tt][3] * sc);
                __builtin_nontemporal_store(u, reinterpret_cast<u16x4*>(dst + tt * 256));
            }
        }
    }
}

// ---------------------------------------------------------------- K2a (FULL)
// Attention only. One (window, 4-head group) per block, one head per wave.
// Fragment loads use the granule-permuted q/k/v layout (see top).
// O written bf16 head-major [pair][tok][32] IN PLACE over qg (normal stores).
__global__ __launch_bounds__(256, 4) void attn_only(
    const unsigned short* __restrict__ qg, const unsigned short* __restrict__ kg,
    const unsigned short* __restrict__ vg, const unsigned short* __restrict__ bm2,
    unsigned short* __restrict__ Og)
{
    __shared__ unsigned short psm_all[4][64 * 64];   // 32 KiB, XOR-swizzled
    __shared__ unsigned short tb_all[4][512];        // 4 KiB transpose bounce
    const int tid = threadIdx.x, wave = tid >> 6, lane = tid & 63;
    const int lo = lane & 15, hi = lane >> 4;
    const int bid = blockIdx.x;
    const int win = bid / 3, e = bid - win * 3;
    const int widx = win & 63;
    const int h = e * 4 + wave;
    const size_t pair = (size_t)(win * 12 + h);
    const unsigned short* qb  = qg + pair * 2048;
    const unsigned short* kbp = kg + pair * 2048;
    const unsigned short* vb  = vg + pair * 2048;
    const unsigned short* bmb = bm2 + (size_t)(widx * 12 + h) * 4096;
    unsigned short* psm = psm_all[wave];
    const int fbase = (hi >> 1) * 1024 + (hi & 1) * 128 + lo * 8;  // q/k frag base

    bf16x8 kf[4];
    #pragma unroll
    for (int ct = 0; ct < 4; ++ct)
        kf[ct] = *reinterpret_cast<const bf16x8*>(kbp + fbase + ct * 256);

    #pragma unroll
    for (int rh = 0; rh < 2; ++rh){
        f32x4 s[2][4];
        __builtin_amdgcn_s_setprio(1);
        #pragma unroll
        for (int rt2 = 0; rt2 < 2; ++rt2){
            bf16x8 qf = *reinterpret_cast<const bf16x8*>(
                qb + fbase + (rh * 2 + rt2) * 256);
            #pragma unroll
            for (int ct = 0; ct < 4; ++ct){
                f32x4 z = {0,0,0,0};
                s[rt2][ct] = MFMA(qf, kf[ct], z, 0, 0, 0);
            }
        }
        __builtin_amdgcn_s_setprio(0);
        #pragma unroll
        for (int rt2 = 0; rt2 < 2; ++rt2)
            #pragma unroll
            for (int ct = 0; ct < 4; ++ct){
                ushort4 bv = *reinterpret_cast<const ushort4*>(
                    bmb + (ct * 16 + lo) * 64 + (rh * 2 + rt2) * 16 + hi * 4);
                s[rt2][ct][0] += b2f(bv.x);
                s[rt2][ct][1] += b2f(bv.y);
                s[rt2][ct][2] += b2f(bv.z);
                s[rt2][ct][3] += b2f(bv.w);
            }
        #pragma unroll
        for (int rt2 = 0; rt2 < 2; ++rt2)
            #pragma unroll
            for (int r4 = 0; r4 < 4; ++r4){
                float mx = fmaxf(fmaxf(s[rt2][0][r4], s[rt2][1][r4]),
                                 fmaxf(s[rt2][2][r4], s[rt2][3][r4]));
                mx = fmaxf(mx, __shfl_xor(mx, 1, 64));
                mx = fmaxf(mx, __shfl_xor(mx, 2, 64));
                mx = fmaxf(mx, __shfl_xor(mx, 4, 64));
                mx = fmaxf(mx, __shfl_xor(mx, 8, 64));
                float e0 = __expf(s[rt2][0][r4] - mx), e1 = __expf(s[rt2][1][r4] - mx);
                float e2 = __expf(s[rt2][2][r4] - mx), e3 = __expf(s[rt2][3][r4] - mx);
                float sm = e0 + e1 + e2 + e3;
                sm += __shfl_xor(sm, 1, 64);
                sm += __shfl_xor(sm, 2, 64);
                sm += __shfl_xor(sm, 4, 64);
                sm += __shfl_xor(sm, 8, 64);
                const float inv = 1.0f / sm;
                const int row = (rh * 2 + rt2) * 16 + hi * 4 + r4;
                const int rsw = row & 7;
                #pragma unroll
                for (int ct = 0; ct < 4; ++ct){
                    const int c = ct * 2 + (lo >> 3);
                    const float ev = (ct == 0 ? e0 : ct == 1 ? e1 : ct == 2 ? e2 : e3);
                    psm[row * 64 + (c ^ rsw) * 8 + (lo & 7)] = f2b(ev * inv);
                }
            }
    }
    asm volatile("" ::: "memory");

    f32x4 o[4][2];
    #pragma unroll
    for (int rt = 0; rt < 4; ++rt){ o[rt][0] = {0,0,0,0}; o[rt][1] = {0,0,0,0}; }
    #pragma unroll
    for (int ks = 0; ks < 2; ++ks){
        bf16x8 vf[2];
        #pragma unroll
        for (int ct2 = 0; ct2 < 2; ++ct2)
            vf[ct2] = *reinterpret_cast<const bf16x8*>(
                vb + ct2 * 1024 + (ks * 2 + (hi >> 1)) * 256 + (hi & 1) * 128 + lo * 8);
        __builtin_amdgcn_s_setprio(1);
        #pragma unroll
        for (int rt = 0; rt < 4; ++rt){
            const int row = rt * 16 + lo;
            const int c = ks * 4 + hi;
            bf16x8 pa = *reinterpret_cast<const bf16x8*>(
                psm + row * 64 + (c ^ (row & 7)) * 8);
            o[rt][0] = MFMA(pa, vf[0], o[rt][0], 0, 0, 0);
            o[rt][1] = MFMA(pa, vf[1], o[rt][1], 0, 0, 0);
        }
        __builtin_amdgcn_s_setprio(0);
    }

    // O epilogue: C-layout -> [tok][32] via LDS bounce -> 1KB coalesced store.
    // NORMAL store (cached): proj_only reads this back immediately.
    unsigned short* tb = tb_all[wave];
    #pragma unroll
    for (int rt = 0; rt < 4; ++rt){
        asm volatile("" ::: "memory");
        #pragma unroll
        for (int ct2 = 0; ct2 < 2; ++ct2)
            #pragma unroll
            for (int r4 = 0; r4 < 4; ++r4)
                tb[(hi * 4 + r4) * 32 + ct2 * 16 + lo] = f2b(o[rt][ct2][r4]);
        asm volatile("" ::: "memory");
        u16x8 v = *reinterpret_cast<const u16x8*>(tb + (lane >> 2) * 32 + (lane & 3) * 8);
        *reinterpret_cast<u16x8*>(
            Og + pair * 2048 + rt * 512 + (lane >> 2) * 32 + (lane & 3) * 8) = v;
        asm volatile("" ::: "memory");
    }
}

// ---------------------------------------------------------------- K2b (FULL)
// Proj GEMM. HALF-window per block (32 tokens): LDS 24.5K. Stage O (head-major
// bf16, L2-hot) into swizzled As; packed-B GEMM; epilogue bounces f32 through
// LDS so stores are FULL-LINE nontemporal row writes.
__global__ __launch_bounds__(256, 4) void proj_only(
    const unsigned short* __restrict__ Og, const unsigned short* __restrict__ wprojP,
    const float* __restrict__ bproj, float* __restrict__ out)
{
    __shared__ __attribute__((aligned(16))) unsigned char smem[25088];
    unsigned short* As = reinterpret_cast<unsigned short*>(smem);  // 32x384 bf16 swz
    float* Asf = reinterpret_cast<float*>(smem);                   // 16x392 f32 bounce
    const int tid = threadIdx.x, wave = tid >> 6, lane = tid & 63;
    const int lo = lane & 15, hi = lane >> 4;
    const int blk = blockIdx.x;
    const int win = blk >> 1, half = blk & 1;
    const int widx = win & 63, wh = widx >> 3, ww = widx & 7, b = win >> 6;

    { // stage 32 tokens x 384 cols; col chunk c -> head c>>2, sub-chunk c&3
        const int r = tid >> 3;              // local row 0..31
        const int c0 = tid & 7;
        const int tokg = half * 32 + r;
        #pragma unroll
        for (int i = 0; i < 6; ++i){
            const int c = c0 + i * 8;        // chunk 0..47
            const int h = c >> 2;
            bf16x8 v = *reinterpret_cast<const bf16x8*>(
                Og + (size_t)(win * 12 + h) * 2048 + tokg * 32 + (c & 3) * 8);
            const int cs = (c & ~7) | ((c & 7) ^ (r & 7));
            *reinterpret_cast<bf16x8*>(As + r * 384 + cs * 8) = v;
        }
    }
    __syncthreads();

    // GEMM: wave owns 96 output cols (6 tiles); 2 row-tiles (32 tokens)
    f32x4 acc[2][6];
    #pragma unroll
    for (int rt = 0; rt < 2; ++rt)
        #pragma unroll
        for (int ct = 0; ct < 6; ++ct) acc[rt][ct] = {0,0,0,0};
    #pragma unroll
    for (int kf = 0; kf < 12; ++kf){
        bf16x8 bfr[6];
        #pragma unroll
        for (int ct = 0; ct < 6; ++ct){
            const int t = wave * 6 + ct;
            bfr[ct] = *reinterpret_cast<const bf16x8*>(
                wprojP + (size_t)(t * 12 + kf) * 512 + lane * 8);
        }
        const int c = kf * 4 + hi;
        #pragma unroll
        for (int rt = 0; rt < 2; ++rt){
            const int r = rt * 16 + lo;
            const int cs = (c & ~7) | ((c & 7) ^ (r & 7));
            bf16x8 af = *reinterpret_cast<const bf16x8*>(As + r * 384 + cs * 8);
            #pragma unroll
            for (int ct = 0; ct < 6; ++ct)
                acc[rt][ct] = MFMA(af, bfr[ct], acc[rt][ct], 0, 0, 0);
        }
    }

    // epilogue: two 16-token rounds through f32 LDS -> full-row nt stores
    #pragma unroll
    for (int p = 0; p < 2; ++p){
        __syncthreads();
        #pragma unroll
        for (int ct = 0; ct < 6; ++ct){
            const int col = wave * 96 + ct * 16 + lo;
            const float bv = bproj[col];
            #pragma unroll
            for (int r4 = 0; r4 < 4; ++r4)
                Asf[(hi * 4 + r4) * 392 + col] = acc[p][ct][r4] + bv;
        }
        __syncthreads();
        const int row = tid >> 4, tcol = tid & 15;
        const int tok = half * 32 + p * 16 + row;
        const int ih = tok >> 3, iw = tok & 7;
        const int gh = (wh * 8 + ih + 4) & 63, gw = (ww * 8 + iw + 4) & 63;
        float* orow = out + ((size_t)(b * 4096 + gh * 64 + gw)) * 384;
        #pragma unroll
        for (int j = 0; j < 6; ++j){
            f32x4 v = *reinterpret_cast<const f32x4*>(Asf + row * 392 + j * 64 + tcol * 4);
            __builtin_nontemporal_store(v, reinterpret_cast<f32x4*>(orow + j * 64 + tcol * 4));
        }
    }
}

// ---------------------------------------------------------------- prep (MID/LOW)
__global__ void transpose_weights(const float* __restrict__ wqkv,
                                  const float* __restrict__ wproj,
                                  unsigned short* __restrict__ wqkvT,
                                  unsigned short* __restrict__ wprojT){
    int i = blockIdx.x * 256 + threadIdx.x;
    if (i < 1152 * 384){ int j = i / 384, k = i % 384; wqkvT[i] = f2b(wqkv[k * 1152 + j]); }
    i -= 1152 * 384;
    if (i >= 0 && i < 384 * 384){ int j = i / 384, k = i % 384; wprojT[i] = f2b(wproj[k * 384 + j]); }
}

// ---------------------------------------------------------------- MID fused (no proj)
__global__ __launch_bounds__(256) void fused_noproj(
    const float* __restrict__ x, const float* __restrict__ emb,
    const int* __restrict__ indices, const float* __restrict__ mask,
    const unsigned short* __restrict__ wqkvT, unsigned short* __restrict__ Og)
{
    __shared__ unsigned short smem[37120];
    unsigned short* xw = smem;
    unsigned short* qT = smem + 25088;
    unsigned short* kT = smem + 27648;
    unsigned short* vT = smem + 30208;
    unsigned short* pT = smem + 32512;

    const int tid = threadIdx.x, wave = tid >> 6, lane = tid & 63;
    const int lo = lane & 15, hi = lane >> 4;
    const int blk = blockIdx.x, b = blk >> 6, widx = blk & 63;
    const int wh = widx >> 3, wwi = widx & 7;

    {
        const int n = tid >> 2, qp = tid & 3;
        const int ih = n >> 3, iw = n & 7;
        const int gh = ((wh * 8 + ih) + 4) & 63, gw = ((wwi * 8 + iw) + 4) & 63;
        const size_t src = ((size_t)b * 4096 + gh * 64 + gw) * 384 + qp * 96;
        const float4* gp = reinterpret_cast<const float4*>(x + src);
        unsigned short* dst = xw + n * 392 + qp * 96;
        #pragma unroll
        for (int i = 0; i < 24; ++i){
            float4 f = gp[i];
            ushort4 u;
            u.x = f2b(f.x); u.y = f2b(f.y); u.z = f2b(f.z); u.w = f2b(f.w);
            *reinterpret_cast<ushort4*>(dst + i * 4) = u;
        }
    }
    __syncthreads();

    for (int h = 0; h < NHEADS; ++h){
        #pragma unroll
        for (int j = 0; j < 6; ++j){
            const int t = wave * 6 + j;
            const int m = t >> 3, tt = t & 7;
            const int tr = tt >> 1, tc = tt & 1;
            const int col = m * 384 + h * 32 + tc * 16 + lo;
            f32x4 acc = {0.f, 0.f, 0.f, 0.f};
            #pragma unroll
            for (int kb = 0; kb < 12; ++kb){
                bf16x8 a = *reinterpret_cast<const bf16x8*>(xw + (tr * 16 + lo) * 392 + kb * 32 + hi * 8);
                bf16x8 bb = *reinterpret_cast<const bf16x8*>(wqkvT + (size_t)col * 384 + kb * 32 + hi * 8);
                acc = MFMA(a, bb, acc, 0, 0, 0);
            }
            #pragma unroll
            for (int r = 0; r < 4; ++r){
                const int token = tr * 16 + hi * 4 + r;
                const int d = tc * 16 + lo;
                if (m == 0)      qT[token * 40 + d] = f2b(acc[r] * SCALE);
                else if (m == 1) kT[token * 40 + d] = f2b(acc[r]);
                else             vT[d * 72 + token] = f2b(acc[r]);
            }
        }
        __syncthreads();
        {
            const int mi = wave;
            bf16x8 qf = *reinterpret_cast<const bf16x8*>(qT + (mi * 16 + lo) * 40 + hi * 8);
            f32x4 s[4];
            #pragma unroll
            for (int ni = 0; ni < 4; ++ni){
                bf16x8 kfr = *reinterpret_cast<const bf16x8*>(kT + (ni * 16 + lo) * 40 + hi * 8);
                f32x4 z = {0.f, 0.f, 0.f, 0.f};
                s[ni] = MFMA(qf, kfr, z, 0, 0, 0);
            }
            #pragma unroll
            for (int ni = 0; ni < 4; ++ni){
                const int kk = ni * 16 + lo;
                #pragma unroll
                for (int r = 0; r < 4; ++r){
                    const int qq = mi * 16 + hi * 4 + r;
                    const int ij = qq * 64 + kk;
                    s[ni][r] += emb[indices[ij] * 12 + h] + emb[indices[4096 + ij] * 12 + h]
                              + mask[widx * 4096 + ij];
                }
            }
            #pragma unroll
            for (int r = 0; r < 4; ++r){
                float mx = fmaxf(fmaxf(s[0][r], s[1][r]), fmaxf(s[2][r], s[3][r]));
                mx = fmaxf(mx, __shfl_xor(mx, 1, 64));
                mx = fmaxf(mx, __shfl_xor(mx, 2, 64));
                mx = fmaxf(mx, __shfl_xor(mx, 4, 64));
                mx = fmaxf(mx, __shfl_xor(mx, 8, 64));
                float e0 = __expf(s[0][r] - mx), e1 = __expf(s[1][r] - mx);
                float e2 = __expf(s[2][r] - mx), e3 = __expf(s[3][r] - mx);
                float sm = e0 + e1 + e2 + e3;
                sm += __shfl_xor(sm, 1, 64);
                sm += __shfl_xor(sm, 2, 64);
                sm += __shfl_xor(sm, 4, 64);
                sm += __shfl_xor(sm, 8, 64);
                float inv = 1.0f / sm;
                const int qq = mi * 16 + hi * 4 + r;
                pT[qq * 72 +  0 + lo] = f2b(e0 * inv);
                pT[qq * 72 + 16 + lo] = f2b(e1 * inv);
                pT[qq * 72 + 32 + lo] = f2b(e2 * inv);
                pT[qq * 72 + 48 + lo] = f2b(e3 * inv);
            }
        }
        __syncthreads();
        {
            const int tr = wave;
            #pragma unroll
            for (int tc = 0; tc < 2; ++tc){
                f32x4 acc = {0.f, 0.f, 0.f, 0.f};
                #pragma unroll
                for (int st = 0; st < 2; ++st){
                    bf16x8 a = *reinterpret_cast<const bf16x8*>(pT + (tr * 16 + lo) * 72 + st * 32 + hi * 8);
                    bf16x8 bb = *reinterpret_cast<const bf16x8*>(vT + (tc * 16 + lo) * 72 + st * 32 + hi * 8);
                    acc = MFMA(a, bb, acc, 0, 0, 0);
                }
                #pragma unroll
                for (int r = 0; r < 4; ++r){
                    const int token = tr * 16 + hi * 4 + r;
                    Og[((size_t)blk * 64 + token) * 384 + h * 32 + tc * 16 + lo] = f2b(acc[r]);
                }
            }
        }
        __syncthreads();
    }
}

// ---------------------------------------------------------------- MID proj
__global__ __launch_bounds__(256) void proj_gemm_T(
    const unsigned short* __restrict__ Og, const unsigned short* __restrict__ wprojT,
    const float* __restrict__ bproj, float* __restrict__ out)
{
    __shared__ unsigned short As[64 * 384];
    const int tid = threadIdx.x, wave = tid >> 6, lane = tid & 63;
    const int lo = lane & 15, hi = lane >> 4;
    const int win = blockIdx.x;
    const int widx = win & 63, wh = widx >> 3, ww = widx & 7, b = win >> 6;

    {
        const int r = tid >> 2;
        const unsigned short* src = Og + ((size_t)win * 64 + r) * 384;
        const int sw = r & 7;
        #pragma unroll
        for (int i = 0; i < 12; ++i){
            const int c = (tid & 3) + i * 4;
            bf16x8 v = *reinterpret_cast<const bf16x8*>(src + c * 8);
            const int cs = (c & ~7) | ((c & 7) ^ sw);
            *reinterpret_cast<bf16x8*>(As + r * 384 + cs * 8) = v;
        }
    }
    __syncthreads();

    #pragma unroll 1
    for (int nc = 0; nc < 3; ++nc){
        f32x4 acc[4][2];
        #pragma unroll
        for (int rt = 0; rt < 4; ++rt){ acc[rt][0] = {0,0,0,0}; acc[rt][1] = {0,0,0,0}; }
        #pragma unroll
        for (int kb = 0; kb < 6; ++kb){
            bf16x8 bf[2][2];
            #pragma unroll
            for (int ct = 0; ct < 2; ++ct)
                #pragma unroll
                for (int ks = 0; ks < 2; ++ks){
                    const int col = nc * 128 + wave * 32 + ct * 16 + lo;
                    bf[ct][ks] = *reinterpret_cast<const bf16x8*>(
                        wprojT + (size_t)col * 384 + kb * 64 + ks * 32 + hi * 8);
                }
            #pragma unroll
            for (int ks = 0; ks < 2; ++ks)
                #pragma unroll
                for (int rt = 0; rt < 4; ++rt){
                    const int r = rt * 16 + lo;
                    const int c = kb * 8 + ks * 4 + hi;
                    const int cs = (c & ~7) | ((c & 7) ^ (r & 7));
                    bf16x8 af = *reinterpret_cast<const bf16x8*>(As + r * 384 + cs * 8);
                    acc[rt][0] = MFMA(af, bf[0][ks], acc[rt][0], 0, 0, 0);
                    acc[rt][1] = MFMA(af, bf[1][ks], acc[rt][1], 0, 0, 0);
                }
        }
        #pragma unroll
        for (int rt = 0; rt < 4; ++rt)
            #pragma unroll
            for (int ct = 0; ct < 2; ++ct){
                const int col = nc * 128 + wave * 32 + ct * 16 + lo;
                const float bv = bproj[col];
                #pragma unroll
                for (int r4 = 0; r4 < 4; ++r4){
                    const int tok = rt * 16 + hi * 4 + r4;
                    const int ih = tok >> 3, iw = tok & 7;
                    const int gh = (wh * 8 + ih + 4) & 63, gw = (ww * 8 + iw + 4) & 63;
                    out[((size_t)(b * 4096 + gh * 64 + gw)) * 384 + col] =
                        acc[rt][ct][r4] + bv;
                }
            }
    }
}

// ---------------------------------------------------------------- LOW fallback
static __device__ __forceinline__ bf16x8 load_bT(const unsigned short* __restrict__ WT,
                                                 const float* __restrict__ Worig,
                                                 int useT, int col, int k0, int ldOrig){
    if (useT){
        return *reinterpret_cast<const bf16x8*>(WT + (size_t)col * 384 + k0);
    } else {
        union { bf16x8 v; unsigned short s[8]; } u;
        #pragma unroll
        for (int i = 0; i < 8; ++i) u.s[i] = f2b(Worig[(size_t)(k0 + i) * ldOrig + col]);
        return u.v;
    }
}

__global__ __launch_bounds__(256) void swin_attn_kernel(
    const float* __restrict__ x, const float* __restrict__ wqkv,
    const float* __restrict__ wproj, const float* __restrict__ bproj,
    const float* __restrict__ emb, const int* __restrict__ indices,
    const float* __restrict__ mask, const unsigned short* __restrict__ wqkvT,
    const unsigned short* __restrict__ wprojT, int useT, float* __restrict__ out)
{
    __shared__ unsigned short smem[62208];
    unsigned short* xw = smem;
    unsigned short* O  = smem + 25088;
    unsigned short* qT = smem + 50176;
    unsigned short* kT = smem + 52736;
    unsigned short* vT = smem + 55296;
    unsigned short* pT = smem + 57600;

    const int tid = threadIdx.x, wave = tid >> 6, lane = tid & 63;
    const int lo = lane & 15, hi = lane >> 4;
    const int blk = blockIdx.x, b = blk >> 6, widx = blk & 63;
    const int wh = widx >> 3, wwi = widx & 7;

    {
        const int n = tid >> 2, qp = tid & 3;
        const int ih = n >> 3, iw = n & 7;
        const int gh = ((wh * 8 + ih) + 4) & 63, gw = ((wwi * 8 + iw) + 4) & 63;
        const size_t src = ((size_t)b * 4096 + gh * 64 + gw) * 384 + qp * 96;
        const float4* gp = reinterpret_cast<const float4*>(x + src);
        unsigned short* dst = xw + n * 392 + qp * 96;
        #pragma unroll
        for (int i = 0; i < 24; ++i){
            float4 f = gp[i];
            ushort4 u;
            u.x = f2b(f.x); u.y = f2b(f.y); u.z = f2b(f.z); u.w = f2b(f.w);
            *reinterpret_cast<ushort4*>(dst + i * 4) = u;
        }
    }
    __syncthreads();

    for (int h = 0; h < NHEADS; ++h){
        #pragma unroll
        for (int j = 0; j < 6; ++j){
            const int t = wave * 6 + j;
            const int m = t >> 3, tt = t & 7;
            const int tr = tt >> 1, tc = tt & 1;
            const int col = m * 384 + h * 32 + tc * 16 + lo;
            f32x4 acc = {0.f, 0.f, 0.f, 0.f};
            #pragma unroll
            for (int kb = 0; kb < 12; ++kb){
                bf16x8 a = *reinterpret_cast<const bf16x8*>(xw + (tr * 16 + lo) * 392 + kb * 32 + hi * 8);
                bf16x8 bb = load_bT(wqkvT, wqkv, useT, col, kb * 32 + hi * 8, 1152);
                acc = MFMA(a, bb, acc, 0, 0, 0);
            }
            #pragma unroll
            for (int r = 0; r < 4; ++r){
                const int token = tr * 16 + hi * 4 + r;
                const int d = tc * 16 + lo;
                if (m == 0)      qT[token * 40 + d] = f2b(acc[r] * SCALE);
                else if (m == 1) kT[token * 40 + d] = f2b(acc[r]);
                else             vT[d * 72 + token] = f2b(acc[r]);
            }
        }
        __syncthreads();
        {
            const int mi = wave;
            bf16x8 qf = *reinterpret_cast<const bf16x8*>(qT + (mi * 16 + lo) * 40 + hi * 8);
            f32x4 s[4];
            #pragma unroll
            for (int ni = 0; ni < 4; ++ni){
                bf16x8 kfr = *reinterpret_cast<const bf16x8*>(kT + (ni * 16 + lo) * 40 + hi * 8);
                f32x4 z = {0.f, 0.f, 0.f, 0.f};
                s[ni] = MFMA(qf, kfr, z, 0, 0, 0);
            }
            #pragma unroll
            for (int ni = 0; ni < 4; ++ni){
                const int kk = ni * 16 + lo;
                #pragma unroll
                for (int r = 0; r < 4; ++r){
                    const int qq = mi * 16 + hi * 4 + r;
                    const int ij = qq * 64 + kk;
                    s[ni][r] += emb[indices[ij] * 12 + h] + emb[indices[4096 + ij] * 12 + h]
                              + mask[widx * 4096 + ij];
                }
            }
            #pragma unroll
            for (int r = 0; r < 4; ++r){
                float mx = fmaxf(fmaxf(s[0][r], s[1][r]), fmaxf(s[2][r], s[3][r]));
                mx = fmaxf(mx, __shfl_xor(mx, 1, 64));
                mx = fmaxf(mx, __shfl_xor(mx, 2, 64));
                mx = fmaxf(mx, __shfl_xor(mx, 4, 64));
                mx = fmaxf(mx, __shfl_xor(mx, 8, 64));
                float e0 = __expf(s[0][r] - mx), e1 = __expf(s[1][r] - mx);
                float e2 = __expf(s[2][r] - mx), e3 = __expf(s[3][r] - mx);
                float sm = e0 + e1 + e2 + e3;
                sm += __shfl_xor(sm, 1, 64);
                sm += __shfl_xor(sm, 2, 64);
                sm += __shfl_xor(sm, 4, 64);
                sm += __shfl_xor(sm, 8, 64);
                float inv = 1.0f / sm;
                const int qq = mi * 16 + hi * 4 + r;
                pT[qq * 72 +  0 + lo] = f2b(e0 * inv);
                pT[qq * 72 + 16 + lo] = f2b(e1 * inv);
                pT[qq * 72 + 32 + lo] = f2b(e2 * inv);
                pT[qq * 72 + 48 + lo] = f2b(e3 * inv);
            }
        }
        __syncthreads();
        {
            const int tr = wave;
            #pragma unroll
            for (int tc = 0; tc < 2; ++tc){
                f32x4 acc = {0.f, 0.f, 0.f, 0.f};
                #pragma unroll
                for (int st = 0; st < 2; ++st){
                    bf16x8 a = *reinterpret_cast<const bf16x8*>(pT + (tr * 16 + lo) * 72 + st * 32 + hi * 8);
                    bf16x8 bb = *reinterpret_cast<const bf16x8*>(vT + (tc * 16 + lo) * 72 + st * 32 + hi * 8);
                    acc = MFMA(a, bb, acc, 0, 0, 0);
                }
                #pragma unroll
                for (int r = 0; r < 4; ++r){
                    const int token = tr * 16 + hi * 4 + r;
                    O[token * 392 + h * 32 + tc * 16 + lo] = f2b(acc[r]);
                }
            }
        }
        __syncthreads();
    }
    {
        const int tr = wave;
        bf16x8 afr[12];
        #pragma unroll
        for (int kb = 0; kb < 12; ++kb)
            afr[kb] = *reinterpret_cast<const bf16x8*>(O + (tr * 16 + lo) * 392 + kb * 32 + hi * 8);
        for (int tc = 0; tc < 24; ++tc){
            const int col = tc * 16 + lo;
            f32x4 acc = {0.f, 0.f, 0.f, 0.f};
            #pragma unroll
            for (int kb = 0; kb < 12; ++kb){
                bf16x8 bb = load_bT(wprojT, wproj, useT, col, kb * 32 + hi * 8, 384);
                acc = MFMA(afr[kb], bb, acc, 0, 0, 0);
            }
            const float bv = bproj[col];
            #pragma unroll
            for (int r = 0; r < 4; ++r){
                const int token = tr * 16 + hi * 4 + r;
                const int ih = token >> 3, iw = token & 7;
                const int gh = ((wh * 8 + ih) + 4) & 63, gw = ((wwi * 8 + iw) + 4) & 63;
                out[((size_t)b * 4096 + gh * 64 + gw) * 384 + col] = acc[r] + bv;
            }
        }
    }
}

// ---------------------------------------------------------------- launch
extern "C" void kernel_launch(void* const* d_in, const int* in_sizes, int n_in,
                              void* d_out, int out_size, void* d_ws, size_t ws_size,
                              hipStream_t stream){
    const float* x     = (const float*)d_in[0];
    const float* wqkv  = (const float*)d_in[1];
    const float* wproj = (const float*)d_in[2];
    const float* bproj = (const float*)d_in[3];
    const float* emb   = (const float*)d_in[4];
    const int*   idx   = (const int*)d_in[5];
    const float* mask  = (const float*)d_in[6];
    float* out = (float*)d_out;

    const int B = in_sizes[0] / (4096 * 384);
    const int NWIN = B * 64;

    unsigned short* ws = (unsigned short*)d_ws;
    const size_t W1 = (size_t)1152 * 384;           // wqkvP elems
    const size_t W2 = (size_t)384 * 384;            // wprojP elems
    const size_t BM = (size_t)64 * 12 * 4096;       // bm2 elems
    const size_t QE = (size_t)NWIN * 12 * 64 * 32;  // q/k/v elems each
    const size_t full_need = (W1 + W2 + BM + 3 * QE) * 2;
    const size_t mid_need  = (W1 + W2 + QE) * 2;
    const size_t low_need  = (W1 + W2) * 2;

    if (d_ws && ws_size >= full_need){
        unsigned short* wqkvP  = ws;
        unsigned short* wprojP = ws + W1;
        unsigned short* bm2    = ws + W1 + W2;
        unsigned short* qg     = bm2 + BM;
        unsigned short* kg     = qg + QE;
        unsigned short* vg     = kg + QE;
        prep_full<<<dim3(14592), dim3(256), 0, stream>>>(wqkv, wproj, emb, idx, mask,
                                                         wqkvP, wprojP, bm2);
        qkv_gemm<<<dim3(NWIN), dim3(256), 0, stream>>>(x, wqkvP, qg, kg, vg);
        // O overwrites qg in place (each wave consumes its q before writing O)
        attn_only<<<dim3(NWIN * 3), dim3(256), 0, stream>>>(qg, kg, vg, bm2, qg);
        proj_only<<<dim3(NWIN * 2), dim3(256), 0, stream>>>(qg, wprojP, bproj, out);
    } else if (d_ws && ws_size >= mid_need){
        unsigned short* wqkvT  = ws;
        unsigned short* wprojT = ws + W1;
        unsigned short* Og     = ws + W1 + W2;
        transpose_weights<<<dim3(2304), dim3(256), 0, stream>>>(wqkv, wproj, wqkvT, wprojT);
        fused_noproj<<<dim3(NWIN), dim3(256), 0, stream>>>(x, emb, idx, mask, wqkvT, Og);
        proj_gemm_T<<<dim3(NWIN), dim3(256), 0, stream>>>(Og, wprojT, bproj, out);
    } else {
        unsigned short* wqkvT  = ws;
        unsigned short* wprojT = ws ? ws + W1 : nullptr;
        const int useT = (d_ws != nullptr && ws_size >= low_need) ? 1 : 0;
        if (useT)
            transpose_weights<<<dim3(2304), dim3(256), 0, stream>>>(wqkv, wproj, wqkvT, wprojT);
        swin_attn_kernel<<<dim3(NWIN), dim3(256), 0, stream>>>(
            x, wqkv, wproj, bproj, emb, idx, mask, wqkvT, wprojT, useT, out);
    }
}

// Round 5
// 380.315 us; speedup vs baseline: 3.5846x; 3.5846x over previous
//
#include <hip/hip_runtime.h>
#include <hip/hip_bf16.h>

typedef __bf16 bf16x8 __attribute__((ext_vector_type(8)));
typedef float f32x4 __attribute__((ext_vector_type(4)));
typedef float f32x4v __attribute__((ext_vector_type(4)));
typedef unsigned short u16x8 __attribute__((ext_vector_type(8)));
typedef unsigned short u16x4 __attribute__((ext_vector_type(4)));

#define NHEADS 12
#define SCALE 0.05103103630798288f  /* 384^-0.5 */
#define MFMA __builtin_amdgcn_mfma_f32_16x16x32_bf16

static __device__ __forceinline__ unsigned short f2b(float f){
    unsigned u = __float_as_uint(f);
    unsigned r = u + 0x7FFFu + ((u >> 16) & 1u);
    return (unsigned short)(r >> 16);
}
static __device__ __forceinline__ float b2f(unsigned short u){
    union { float f; unsigned u32; } v; v.u32 = ((unsigned)u) << 16; return v.f;
}

// q/k/v global layout (per head-pair, 2048 u16): granule-permuted so BOTH the
// qkv stores (512B contiguous per instruction) and the attn fragment loads
// (16B/lane) are fully coalesced:
//   q/k (element (tok,d)):  off = (d>>4)*1024 + (tok>>4)*256 + ((d>>3)&1)*128
//                                 + (tok&15)*8 + ((d>>2)&1)*4
//   v   (element (d,tok)):  off = (d>>4)*1024 + (tok>>4)*256 + ((tok>>3)&1)*128
//                                 + (d&15)*8 + ((tok>>2)&1)*4

// ---------------------------------------------------------------- prep (FULL)
__global__ void prep_full(const float* __restrict__ wqkv, const float* __restrict__ wproj,
                          const float* __restrict__ emb, const int* __restrict__ indices,
                          const float* __restrict__ mask,
                          unsigned short* __restrict__ wqkvP,
                          unsigned short* __restrict__ wprojP,
                          unsigned short* __restrict__ bm2){
    int i = blockIdx.x * 256 + threadIdx.x;
    if (i < 442368){
        int j = i & 7, rest = i >> 3;
        int ln = rest & 63; rest >>= 6;
        int kf = rest % 12, t = rest / 12;
        int k = kf * 32 + (ln >> 4) * 8 + j;
        int col = t * 16 + (ln & 15);
        wqkvP[i] = f2b(wqkv[k * 1152 + col]);
        return;
    }
    i -= 442368;
    if (i < 147456){
        int j = i & 7, rest = i >> 3;
        int ln = rest & 63; rest >>= 6;
        int kf = rest % 12, t = rest / 12;
        int k = kf * 32 + (ln >> 4) * 8 + j;
        int col = t * 16 + (ln & 15);
        wprojP[i] = f2b(wproj[k * 384 + col]);
        return;
    }
    i -= 147456;
    if (i < 64 * 12 * 4096){
        int w = i / 49152, rem = i % 49152;
        int h = rem / 4096, r2 = rem & 4095;
        int col = r2 >> 6, row = r2 & 63;          // col=key, row=query
        int ij = row * 64 + col;
        float v = emb[indices[ij] * 12 + h] + emb[indices[4096 + ij] * 12 + h]
                + mask[w * 4096 + ij];
        bm2[i] = f2b(v);
    }
}

// ---------------------------------------------------------------- K1 (FULL)
// One window per block, 4 waves. 3 sections (q,k,v); each wave owns 6 W-tiles
// per section. Token-tiles processed in TWO PASSES of 2 so live accumulator
// is acc[6][2] = 48 VGPRs (round-4's acc[6][4]=96 spilled to scratch at the
// 84-VGPR cap of launch_bounds(256,3) -> 4.3GB scratch traffic).
// launch_bounds(256,2) raises the cap to 128. q/k: operand-swapped MFMA
// (d on regs, tok on lanes); v: normal. All stores land in the permuted
// layout -> every store instruction is 512B contiguous NT.
__global__ __launch_bounds__(256, 2) void qkv_gemm(
    const float* __restrict__ x, const unsigned short* __restrict__ wqkvP,
    unsigned short* __restrict__ qg, unsigned short* __restrict__ kg,
    unsigned short* __restrict__ vg)
{
    __shared__ unsigned short As[64 * 384];       // 48 KiB, chunk-swizzled
    const int tid = threadIdx.x, wave = tid >> 6, lane = tid & 63;
    const int lo = lane & 15, hi = lane >> 4;
    const int win = blockIdx.x;
    const int widx = win & 63, wh = widx >> 3, ww = widx & 7, b = win >> 6;

    { // stage A: row = tid>>2, 12 chunks of 8 bf16 each (nt f32 loads)
        const int r = tid >> 2;
        const int ih = r >> 3, iw = r & 7;
        const int gh = (wh * 8 + ih + 4) & 63, gw = (ww * 8 + iw + 4) & 63;
        const float* src = x + ((size_t)(b * 4096 + gh * 64 + gw)) * 384;
        unsigned short* dst = As + r * 384;
        const int sw = r & 7;
        #pragma unroll
        for (int i = 0; i < 12; ++i){
            const int c = (tid & 3) + i * 4;
            f32x4v f0 = __builtin_nontemporal_load(
                reinterpret_cast<const f32x4v*>(src + c * 8));
            f32x4v f1 = __builtin_nontemporal_load(
                reinterpret_cast<const f32x4v*>(src + c * 8 + 4));
            union { bf16x8 v; unsigned short s[8]; } u;
            u.s[0]=f2b(f0[0]); u.s[1]=f2b(f0[1]); u.s[2]=f2b(f0[2]); u.s[3]=f2b(f0[3]);
            u.s[4]=f2b(f1[0]); u.s[5]=f2b(f1[1]); u.s[6]=f2b(f1[2]); u.s[7]=f2b(f1[3]);
            const int cs = (c & ~7) | ((c & 7) ^ sw);
            *reinterpret_cast<bf16x8*>(dst + cs * 8) = u.v;
        }
    }
    __syncthreads();

    #pragma unroll 1
    for (int sec = 0; sec < 3; ++sec){
        const int t0 = sec * 24 + wave * 6;        // first of 6 W-tiles
        const unsigned short* bp = wqkvP + (size_t)t0 * 12 * 512 + lane * 8;
        const float sc = (sec == 0) ? SCALE : 1.0f;
        unsigned short* basep = (sec == 0 ? qg : sec == 1 ? kg : vg);

        #pragma unroll 1
        for (int tp = 0; tp < 2; ++tp){            // token-tile pair
            f32x4 acc[6][2];
            #pragma unroll
            for (int wt = 0; wt < 6; ++wt){ acc[wt][0] = {0,0,0,0}; acc[wt][1] = {0,0,0,0}; }

            #pragma unroll 2
            for (int kf = 0; kf < 12; ++kf){
                bf16x8 bw[6];
                #pragma unroll
                for (int wt = 0; wt < 6; ++wt)
                    bw[wt] = *reinterpret_cast<const bf16x8*>(bp + (wt * 12 + kf) * 512);
                const int c = kf * 4 + hi;
                if (sec < 2){
                    #pragma unroll
                    for (int t2 = 0; t2 < 2; ++t2){
                        const int r = (tp * 2 + t2) * 16 + lo;
                        const int cs = (c & ~7) | ((c & 7) ^ (r & 7));
                        bf16x8 af = *reinterpret_cast<const bf16x8*>(As + r * 384 + cs * 8);
                        #pragma unroll
                        for (int wt = 0; wt < 6; ++wt)
                            acc[wt][t2] = MFMA(bw[wt], af, acc[wt][t2], 0, 0, 0);
                    }
                } else {
                    #pragma unroll
                    for (int t2 = 0; t2 < 2; ++t2){
                        const int r = (tp * 2 + t2) * 16 + lo;
                        const int cs = (c & ~7) | ((c & 7) ^ (r & 7));
                        bf16x8 af = *reinterpret_cast<const bf16x8*>(As + r * 384 + cs * 8);
                        #pragma unroll
                        for (int wt = 0; wt < 6; ++wt)
                            acc[wt][t2] = MFMA(af, bw[wt], acc[wt][t2], 0, 0, 0);
                    }
                }
            }

            // epilogue: permuted layout; each (wt,t2) store op = 512B contiguous
            #pragma unroll
            for (int wt = 0; wt < 6; ++wt){
                const int hloc = wave * 3 + (wt >> 1);
                unsigned short* dst = basep + (size_t)(win * 12 + hloc) * 2048
                                    + (wt & 1) * 1024 + (hi >> 1) * 128 + lo * 8 + (hi & 1) * 4;
                #pragma unroll
                for (int t2 = 0; t2 < 2; ++t2){
                    const int tt = tp * 2 + t2;
                    u16x4 u;
                    u[0] = f2b(acc[wt][t2][0] * sc); u[1] = f2b(acc[wt][t2][1] * sc);
                    u[2] = f2b(acc[wt][t2][2] * sc); u[3] = f2b(acc[wt][t2][3] * sc);
                    __builtin_nontemporal_store(u, reinterpret_cast<u16x4*>(dst + tt * 256));
                }
            }
        }
    }
}

// ---------------------------------------------------------------- K2a (FULL)
// Attention only. One (window, 4-head group) per block, one head per wave.
// Fragment loads use the granule-permuted q/k/v layout (see top).
// O written bf16 head-major [pair][tok][32] IN PLACE over qg (normal stores).
__global__ __launch_bounds__(256, 4) void attn_only(
    const unsigned short* __restrict__ qg, const unsigned short* __restrict__ kg,
    const unsigned short* __restrict__ vg, const unsigned short* __restrict__ bm2,
    unsigned short* __restrict__ Og)
{
    __shared__ unsigned short psm_all[4][64 * 64];   // 32 KiB, XOR-swizzled
    __shared__ unsigned short tb_all[4][512];        // 4 KiB transpose bounce
    const int tid = threadIdx.x, wave = tid >> 6, lane = tid & 63;
    const int lo = lane & 15, hi = lane >> 4;
    const int bid = blockIdx.x;
    const int win = bid / 3, e = bid - win * 3;
    const int widx = win & 63;
    const int h = e * 4 + wave;
    const size_t pair = (size_t)(win * 12 + h);
    const unsigned short* qb  = qg + pair * 2048;
    const unsigned short* kbp = kg + pair * 2048;
    const unsigned short* vb  = vg + pair * 2048;
    const unsigned short* bmb = bm2 + (size_t)(widx * 12 + h) * 4096;
    unsigned short* psm = psm_all[wave];
    const int fbase = (hi >> 1) * 1024 + (hi & 1) * 128 + lo * 8;  // q/k frag base

    bf16x8 kf[4];
    #pragma unroll
    for (int ct = 0; ct < 4; ++ct)
        kf[ct] = *reinterpret_cast<const bf16x8*>(kbp + fbase + ct * 256);

    #pragma unroll
    for (int rh = 0; rh < 2; ++rh){
        f32x4 s[2][4];
        __builtin_amdgcn_s_setprio(1);
        #pragma unroll
        for (int rt2 = 0; rt2 < 2; ++rt2){
            bf16x8 qf = *reinterpret_cast<const bf16x8*>(
                qb + fbase + (rh * 2 + rt2) * 256);
            #pragma unroll
            for (int ct = 0; ct < 4; ++ct){
                f32x4 z = {0,0,0,0};
                s[rt2][ct] = MFMA(qf, kf[ct], z, 0, 0, 0);
            }
        }
        __builtin_amdgcn_s_setprio(0);
        #pragma unroll
        for (int rt2 = 0; rt2 < 2; ++rt2)
            #pragma unroll
            for (int ct = 0; ct < 4; ++ct){
                ushort4 bv = *reinterpret_cast<const ushort4*>(
                    bmb + (ct * 16 + lo) * 64 + (rh * 2 + rt2) * 16 + hi * 4);
                s[rt2][ct][0] += b2f(bv.x);
                s[rt2][ct][1] += b2f(bv.y);
                s[rt2][ct][2] += b2f(bv.z);
                s[rt2][ct][3] += b2f(bv.w);
            }
        #pragma unroll
        for (int rt2 = 0; rt2 < 2; ++rt2)
            #pragma unroll
            for (int r4 = 0; r4 < 4; ++r4){
                float mx = fmaxf(fmaxf(s[rt2][0][r4], s[rt2][1][r4]),
                                 fmaxf(s[rt2][2][r4], s[rt2][3][r4]));
                mx = fmaxf(mx, __shfl_xor(mx, 1, 64));
                mx = fmaxf(mx, __shfl_xor(mx, 2, 64));
                mx = fmaxf(mx, __shfl_xor(mx, 4, 64));
                mx = fmaxf(mx, __shfl_xor(mx, 8, 64));
                float e0 = __expf(s[rt2][0][r4] - mx), e1 = __expf(s[rt2][1][r4] - mx);
                float e2 = __expf(s[rt2][2][r4] - mx), e3 = __expf(s[rt2][3][r4] - mx);
                float sm = e0 + e1 + e2 + e3;
                sm += __shfl_xor(sm, 1, 64);
                sm += __shfl_xor(sm, 2, 64);
                sm += __shfl_xor(sm, 4, 64);
                sm += __shfl_xor(sm, 8, 64);
                const float inv = 1.0f / sm;
                const int row = (rh * 2 + rt2) * 16 + hi * 4 + r4;
                const int rsw = row & 7;
                #pragma unroll
                for (int ct = 0; ct < 4; ++ct){
                    const int c = ct * 2 + (lo >> 3);
                    const float ev = (ct == 0 ? e0 : ct == 1 ? e1 : ct == 2 ? e2 : e3);
                    psm[row * 64 + (c ^ rsw) * 8 + (lo & 7)] = f2b(ev * inv);
                }
            }
    }
    asm volatile("" ::: "memory");

    f32x4 o[4][2];
    #pragma unroll
    for (int rt = 0; rt < 4; ++rt){ o[rt][0] = {0,0,0,0}; o[rt][1] = {0,0,0,0}; }
    #pragma unroll
    for (int ks = 0; ks < 2; ++ks){
        bf16x8 vf[2];
        #pragma unroll
        for (int ct2 = 0; ct2 < 2; ++ct2)
            vf[ct2] = *reinterpret_cast<const bf16x8*>(
                vb + ct2 * 1024 + (ks * 2 + (hi >> 1)) * 256 + (hi & 1) * 128 + lo * 8);
        __builtin_amdgcn_s_setprio(1);
        #pragma unroll
        for (int rt = 0; rt < 4; ++rt){
            const int row = rt * 16 + lo;
            const int c = ks * 4 + hi;
            bf16x8 pa = *reinterpret_cast<const bf16x8*>(
                psm + row * 64 + (c ^ (row & 7)) * 8);
            o[rt][0] = MFMA(pa, vf[0], o[rt][0], 0, 0, 0);
            o[rt][1] = MFMA(pa, vf[1], o[rt][1], 0, 0, 0);
        }
        __builtin_amdgcn_s_setprio(0);
    }

    // O epilogue: C-layout -> [tok][32] via LDS bounce -> 1KB coalesced store.
    // NORMAL store (cached): proj_only reads this back immediately.
    unsigned short* tb = tb_all[wave];
    #pragma unroll
    for (int rt = 0; rt < 4; ++rt){
        asm volatile("" ::: "memory");
        #pragma unroll
        for (int ct2 = 0; ct2 < 2; ++ct2)
            #pragma unroll
            for (int r4 = 0; r4 < 4; ++r4)
                tb[(hi * 4 + r4) * 32 + ct2 * 16 + lo] = f2b(o[rt][ct2][r4]);
        asm volatile("" ::: "memory");
        u16x8 v = *reinterpret_cast<const u16x8*>(tb + (lane >> 2) * 32 + (lane & 3) * 8);
        *reinterpret_cast<u16x8*>(
            Og + pair * 2048 + rt * 512 + (lane >> 2) * 32 + (lane & 3) * 8) = v;
        asm volatile("" ::: "memory");
    }
}

// ---------------------------------------------------------------- K2b (FULL)
// Proj GEMM. HALF-window per block (32 tokens): LDS 24.5K. Stage O (head-major
// bf16, L2-hot) into swizzled As; packed-B GEMM; epilogue bounces f32 through
// LDS so stores are FULL-LINE nontemporal row writes.
__global__ __launch_bounds__(256, 4) void proj_only(
    const unsigned short* __restrict__ Og, const unsigned short* __restrict__ wprojP,
    const float* __restrict__ bproj, float* __restrict__ out)
{
    __shared__ __attribute__((aligned(16))) unsigned char smem[25088];
    unsigned short* As = reinterpret_cast<unsigned short*>(smem);  // 32x384 bf16 swz
    float* Asf = reinterpret_cast<float*>(smem);                   // 16x392 f32 bounce
    const int tid = threadIdx.x, wave = tid >> 6, lane = tid & 63;
    const int lo = lane & 15, hi = lane >> 4;
    const int blk = blockIdx.x;
    const int win = blk >> 1, half = blk & 1;
    const int widx = win & 63, wh = widx >> 3, ww = widx & 7, b = win >> 6;

    { // stage 32 tokens x 384 cols; col chunk c -> head c>>2, sub-chunk c&3
        const int r = tid >> 3;              // local row 0..31
        const int c0 = tid & 7;
        const int tokg = half * 32 + r;
        #pragma unroll
        for (int i = 0; i < 6; ++i){
            const int c = c0 + i * 8;        // chunk 0..47
            const int h = c >> 2;
            bf16x8 v = *reinterpret_cast<const bf16x8*>(
                Og + (size_t)(win * 12 + h) * 2048 + tokg * 32 + (c & 3) * 8);
            const int cs = (c & ~7) | ((c & 7) ^ (r & 7));
            *reinterpret_cast<bf16x8*>(As + r * 384 + cs * 8) = v;
        }
    }
    __syncthreads();

    // GEMM: wave owns 96 output cols (6 tiles); 2 row-tiles (32 tokens)
    f32x4 acc[2][6];
    #pragma unroll
    for (int rt = 0; rt < 2; ++rt)
        #pragma unroll
        for (int ct = 0; ct < 6; ++ct) acc[rt][ct] = {0,0,0,0};
    #pragma unroll
    for (int kf = 0; kf < 12; ++kf){
        bf16x8 bfr[6];
        #pragma unroll
        for (int ct = 0; ct < 6; ++ct){
            const int t = wave * 6 + ct;
            bfr[ct] = *reinterpret_cast<const bf16x8*>(
                wprojP + (size_t)(t * 12 + kf) * 512 + lane * 8);
        }
        const int c = kf * 4 + hi;
        #pragma unroll
        for (int rt = 0; rt < 2; ++rt){
            const int r = rt * 16 + lo;
            const int cs = (c & ~7) | ((c & 7) ^ (r & 7));
            bf16x8 af = *reinterpret_cast<const bf16x8*>(As + r * 384 + cs * 8);
            #pragma unroll
            for (int ct = 0; ct < 6; ++ct)
                acc[rt][ct] = MFMA(af, bfr[ct], acc[rt][ct], 0, 0, 0);
        }
    }

    // epilogue: two 16-token rounds through f32 LDS -> full-row nt stores
    #pragma unroll
    for (int p = 0; p < 2; ++p){
        __syncthreads();
        #pragma unroll
        for (int ct = 0; ct < 6; ++ct){
            const int col = wave * 96 + ct * 16 + lo;
            const float bv = bproj[col];
            #pragma unroll
            for (int r4 = 0; r4 < 4; ++r4)
                Asf[(hi * 4 + r4) * 392 + col] = acc[p][ct][r4] + bv;
        }
        __syncthreads();
        const int row = tid >> 4, tcol = tid & 15;
        const int tok = half * 32 + p * 16 + row;
        const int ih = tok >> 3, iw = tok & 7;
        const int gh = (wh * 8 + ih + 4) & 63, gw = (ww * 8 + iw + 4) & 63;
        float* orow = out + ((size_t)(b * 4096 + gh * 64 + gw)) * 384;
        #pragma unroll
        for (int j = 0; j < 6; ++j){
            f32x4 v = *reinterpret_cast<const f32x4*>(Asf + row * 392 + j * 64 + tcol * 4);
            __builtin_nontemporal_store(v, reinterpret_cast<f32x4*>(orow + j * 64 + tcol * 4));
        }
    }
}

// ---------------------------------------------------------------- prep (MID/LOW)
__global__ void transpose_weights(const float* __restrict__ wqkv,
                                  const float* __restrict__ wproj,
                                  unsigned short* __restrict__ wqkvT,
                                  unsigned short* __restrict__ wprojT){
    int i = blockIdx.x * 256 + threadIdx.x;
    if (i < 1152 * 384){ int j = i / 384, k = i % 384; wqkvT[i] = f2b(wqkv[k * 1152 + j]); }
    i -= 1152 * 384;
    if (i >= 0 && i < 384 * 384){ int j = i / 384, k = i % 384; wprojT[i] = f2b(wproj[k * 384 + j]); }
}

// ---------------------------------------------------------------- MID fused (no proj)
__global__ __launch_bounds__(256) void fused_noproj(
    const float* __restrict__ x, const float* __restrict__ emb,
    const int* __restrict__ indices, const float* __restrict__ mask,
    const unsigned short* __restrict__ wqkvT, unsigned short* __restrict__ Og)
{
    __shared__ unsigned short smem[37120];
    unsigned short* xw = smem;
    unsigned short* qT = smem + 25088;
    unsigned short* kT = smem + 27648;
    unsigned short* vT = smem + 30208;
    unsigned short* pT = smem + 32512;

    const int tid = threadIdx.x, wave = tid >> 6, lane = tid & 63;
    const int lo = lane & 15, hi = lane >> 4;
    const int blk = blockIdx.x, b = blk >> 6, widx = blk & 63;
    const int wh = widx >> 3, wwi = widx & 7;

    {
        const int n = tid >> 2, qp = tid & 3;
        const int ih = n >> 3, iw = n & 7;
        const int gh = ((wh * 8 + ih) + 4) & 63, gw = ((wwi * 8 + iw) + 4) & 63;
        const size_t src = ((size_t)b * 4096 + gh * 64 + gw) * 384 + qp * 96;
        const float4* gp = reinterpret_cast<const float4*>(x + src);
        unsigned short* dst = xw + n * 392 + qp * 96;
        #pragma unroll
        for (int i = 0; i < 24; ++i){
            float4 f = gp[i];
            ushort4 u;
            u.x = f2b(f.x); u.y = f2b(f.y); u.z = f2b(f.z); u.w = f2b(f.w);
            *reinterpret_cast<ushort4*>(dst + i * 4) = u;
        }
    }
    __syncthreads();

    for (int h = 0; h < NHEADS; ++h){
        #pragma unroll
        for (int j = 0; j < 6; ++j){
            const int t = wave * 6 + j;
            const int m = t >> 3, tt = t & 7;
            const int tr = tt >> 1, tc = tt & 1;
            const int col = m * 384 + h * 32 + tc * 16 + lo;
            f32x4 acc = {0.f, 0.f, 0.f, 0.f};
            #pragma unroll
            for (int kb = 0; kb < 12; ++kb){
                bf16x8 a = *reinterpret_cast<const bf16x8*>(xw + (tr * 16 + lo) * 392 + kb * 32 + hi * 8);
                bf16x8 bb = *reinterpret_cast<const bf16x8*>(wqkvT + (size_t)col * 384 + kb * 32 + hi * 8);
                acc = MFMA(a, bb, acc, 0, 0, 0);
            }
            #pragma unroll
            for (int r = 0; r < 4; ++r){
                const int token = tr * 16 + hi * 4 + r;
                const int d = tc * 16 + lo;
                if (m == 0)      qT[token * 40 + d] = f2b(acc[r] * SCALE);
                else if (m == 1) kT[token * 40 + d] = f2b(acc[r]);
                else             vT[d * 72 + token] = f2b(acc[r]);
            }
        }
        __syncthreads();
        {
            const int mi = wave;
            bf16x8 qf = *reinterpret_cast<const bf16x8*>(qT + (mi * 16 + lo) * 40 + hi * 8);
            f32x4 s[4];
            #pragma unroll
            for (int ni = 0; ni < 4; ++ni){
                bf16x8 kfr = *reinterpret_cast<const bf16x8*>(kT + (ni * 16 + lo) * 40 + hi * 8);
                f32x4 z = {0.f, 0.f, 0.f, 0.f};
                s[ni] = MFMA(qf, kfr, z, 0, 0, 0);
            }
            #pragma unroll
            for (int ni = 0; ni < 4; ++ni){
                const int kk = ni * 16 + lo;
                #pragma unroll
                for (int r = 0; r < 4; ++r){
                    const int qq = mi * 16 + hi * 4 + r;
                    const int ij = qq * 64 + kk;
                    s[ni][r] += emb[indices[ij] * 12 + h] + emb[indices[4096 + ij] * 12 + h]
                              + mask[widx * 4096 + ij];
                }
            }
            #pragma unroll
            for (int r = 0; r < 4; ++r){
                float mx = fmaxf(fmaxf(s[0][r], s[1][r]), fmaxf(s[2][r], s[3][r]));
                mx = fmaxf(mx, __shfl_xor(mx, 1, 64));
                mx = fmaxf(mx, __shfl_xor(mx, 2, 64));
                mx = fmaxf(mx, __shfl_xor(mx, 4, 64));
                mx = fmaxf(mx, __shfl_xor(mx, 8, 64));
                float e0 = __expf(s[0][r] - mx), e1 = __expf(s[1][r] - mx);
                float e2 = __expf(s[2][r] - mx), e3 = __expf(s[3][r] - mx);
                float sm = e0 + e1 + e2 + e3;
                sm += __shfl_xor(sm, 1, 64);
                sm += __shfl_xor(sm, 2, 64);
                sm += __shfl_xor(sm, 4, 64);
                sm += __shfl_xor(sm, 8, 64);
                float inv = 1.0f / sm;
                const int qq = mi * 16 + hi * 4 + r;
                pT[qq * 72 +  0 + lo] = f2b(e0 * inv);
                pT[qq * 72 + 16 + lo] = f2b(e1 * inv);
                pT[qq * 72 + 32 + lo] = f2b(e2 * inv);
                pT[qq * 72 + 48 + lo] = f2b(e3 * inv);
            }
        }
        __syncthreads();
        {
            const int tr = wave;
            #pragma unroll
            for (int tc = 0; tc < 2; ++tc){
                f32x4 acc = {0.f, 0.f, 0.f, 0.f};
                #pragma unroll
                for (int st = 0; st < 2; ++st){
                    bf16x8 a = *reinterpret_cast<const bf16x8*>(pT + (tr * 16 + lo) * 72 + st * 32 + hi * 8);
                    bf16x8 bb = *reinterpret_cast<const bf16x8*>(vT + (tc * 16 + lo) * 72 + st * 32 + hi * 8);
                    acc = MFMA(a, bb, acc, 0, 0, 0);
                }
                #pragma unroll
                for (int r = 0; r < 4; ++r){
                    const int token = tr * 16 + hi * 4 + r;
                    Og[((size_t)blk * 64 + token) * 384 + h * 32 + tc * 16 + lo] = f2b(acc[r]);
                }
            }
        }
        __syncthreads();
    }
}

// ---------------------------------------------------------------- MID proj
__global__ __launch_bounds__(256) void proj_gemm_T(
    const unsigned short* __restrict__ Og, const unsigned short* __restrict__ wprojT,
    const float* __restrict__ bproj, float* __restrict__ out)
{
    __shared__ unsigned short As[64 * 384];
    const int tid = threadIdx.x, wave = tid >> 6, lane = tid & 63;
    const int lo = lane & 15, hi = lane >> 4;
    const int win = blockIdx.x;
    const int widx = win & 63, wh = widx >> 3, ww = widx & 7, b = win >> 6;

    {
        const int r = tid >> 2;
        const unsigned short* src = Og + ((size_t)win * 64 + r) * 384;
        const int sw = r & 7;
        #pragma unroll
        for (int i = 0; i < 12; ++i){
            const int c = (tid & 3) + i * 4;
            bf16x8 v = *reinterpret_cast<const bf16x8*>(src + c * 8);
            const int cs = (c & ~7) | ((c & 7) ^ sw);
            *reinterpret_cast<bf16x8*>(As + r * 384 + cs * 8) = v;
        }
    }
    __syncthreads();

    #pragma unroll 1
    for (int nc = 0; nc < 3; ++nc){
        f32x4 acc[4][2];
        #pragma unroll
        for (int rt = 0; rt < 4; ++rt){ acc[rt][0] = {0,0,0,0}; acc[rt][1] = {0,0,0,0}; }
        #pragma unroll
        for (int kb = 0; kb < 6; ++kb){
            bf16x8 bf[2][2];
            #pragma unroll
            for (int ct = 0; ct < 2; ++ct)
                #pragma unroll
                for (int ks = 0; ks < 2; ++ks){
                    const int col = nc * 128 + wave * 32 + ct * 16 + lo;
                    bf[ct][ks] = *reinterpret_cast<const bf16x8*>(
                        wprojT + (size_t)col * 384 + kb * 64 + ks * 32 + hi * 8);
                }
            #pragma unroll
            for (int ks = 0; ks < 2; ++ks)
                #pragma unroll
                for (int rt = 0; rt < 4; ++rt){
                    const int r = rt * 16 + lo;
                    const int c = kb * 8 + ks * 4 + hi;
                    const int cs = (c & ~7) | ((c & 7) ^ (r & 7));
                    bf16x8 af = *reinterpret_cast<const bf16x8*>(As + r * 384 + cs * 8);
                    acc[rt][0] = MFMA(af, bf[0][ks], acc[rt][0], 0, 0, 0);
                    acc[rt][1] = MFMA(af, bf[1][ks], acc[rt][1], 0, 0, 0);
                }
        }
        #pragma unroll
        for (int rt = 0; rt < 4; ++rt)
            #pragma unroll
            for (int ct = 0; ct < 2; ++ct){
                const int col = nc * 128 + wave * 32 + ct * 16 + lo;
                const float bv = bproj[col];
                #pragma unroll
                for (int r4 = 0; r4 < 4; ++r4){
                    const int tok = rt * 16 + hi * 4 + r4;
                    const int ih = tok >> 3, iw = tok & 7;
                    const int gh = (wh * 8 + ih + 4) & 63, gw = (ww * 8 + iw + 4) & 63;
                    out[((size_t)(b * 4096 + gh * 64 + gw)) * 384 + col] =
                        acc[rt][ct][r4] + bv;
                }
            }
    }
}

// ---------------------------------------------------------------- LOW fallback
static __device__ __forceinline__ bf16x8 load_bT(const unsigned short* __restrict__ WT,
                                                 const float* __restrict__ Worig,
                                                 int useT, int col, int k0, int ldOrig){
    if (useT){
        return *reinterpret_cast<const bf16x8*>(WT + (size_t)col * 384 + k0);
    } else {
        union { bf16x8 v; unsigned short s[8]; } u;
        #pragma unroll
        for (int i = 0; i < 8; ++i) u.s[i] = f2b(Worig[(size_t)(k0 + i) * ldOrig + col]);
        return u.v;
    }
}

__global__ __launch_bounds__(256) void swin_attn_kernel(
    const float* __restrict__ x, const float* __restrict__ wqkv,
    const float* __restrict__ wproj, const float* __restrict__ bproj,
    const float* __restrict__ emb, const int* __restrict__ indices,
    const float* __restrict__ mask, const unsigned short* __restrict__ wqkvT,
    const unsigned short* __restrict__ wprojT, int useT, float* __restrict__ out)
{
    __shared__ unsigned short smem[62208];
    unsigned short* xw = smem;
    unsigned short* O  = smem + 25088;
    unsigned short* qT = smem + 50176;
    unsigned short* kT = smem + 52736;
    unsigned short* vT = smem + 55296;
    unsigned short* pT = smem + 57600;

    const int tid = threadIdx.x, wave = tid >> 6, lane = tid & 63;
    const int lo = lane & 15, hi = lane >> 4;
    const int blk = blockIdx.x, b = blk >> 6, widx = blk & 63;
    const int wh = widx >> 3, wwi = widx & 7;

    {
        const int n = tid >> 2, qp = tid & 3;
        const int ih = n >> 3, iw = n & 7;
        const int gh = ((wh * 8 + ih) + 4) & 63, gw = ((wwi * 8 + iw) + 4) & 63;
        const size_t src = ((size_t)b * 4096 + gh * 64 + gw) * 384 + qp * 96;
        const float4* gp = reinterpret_cast<const float4*>(x + src);
        unsigned short* dst = xw + n * 392 + qp * 96;
        #pragma unroll
        for (int i = 0; i < 24; ++i){
            float4 f = gp[i];
            ushort4 u;
            u.x = f2b(f.x); u.y = f2b(f.y); u.z = f2b(f.z); u.w = f2b(f.w);
            *reinterpret_cast<ushort4*>(dst + i * 4) = u;
        }
    }
    __syncthreads();

    for (int h = 0; h < NHEADS; ++h){
        #pragma unroll
        for (int j = 0; j < 6; ++j){
            const int t = wave * 6 + j;
            const int m = t >> 3, tt = t & 7;
            const int tr = tt >> 1, tc = tt & 1;
            const int col = m * 384 + h * 32 + tc * 16 + lo;
            f32x4 acc = {0.f, 0.f, 0.f, 0.f};
            #pragma unroll
            for (int kb = 0; kb < 12; ++kb){
                bf16x8 a = *reinterpret_cast<const bf16x8*>(xw + (tr * 16 + lo) * 392 + kb * 32 + hi * 8);
                bf16x8 bb = load_bT(wqkvT, wqkv, useT, col, kb * 32 + hi * 8, 1152);
                acc = MFMA(a, bb, acc, 0, 0, 0);
            }
            #pragma unroll
            for (int r = 0; r < 4; ++r){
                const int token = tr * 16 + hi * 4 + r;
                const int d = tc * 16 + lo;
                if (m == 0)      qT[token * 40 + d] = f2b(acc[r] * SCALE);
                else if (m == 1) kT[token * 40 + d] = f2b(acc[r]);
                else             vT[d * 72 + token] = f2b(acc[r]);
            }
        }
        __syncthreads();
        {
            const int mi = wave;
            bf16x8 qf = *reinterpret_cast<const bf16x8*>(qT + (mi * 16 + lo) * 40 + hi * 8);
            f32x4 s[4];
            #pragma unroll
            for (int ni = 0; ni < 4; ++ni){
                bf16x8 kfr = *reinterpret_cast<const bf16x8*>(kT + (ni * 16 + lo) * 40 + hi * 8);
                f32x4 z = {0.f, 0.f, 0.f, 0.f};
                s[ni] = MFMA(qf, kfr, z, 0, 0, 0);
            }
            #pragma unroll
            for (int ni = 0; ni < 4; ++ni){
                const int kk = ni * 16 + lo;
                #pragma unroll
                for (int r = 0; r < 4; ++r){
                    const int qq = mi * 16 + hi * 4 + r;
                    const int ij = qq * 64 + kk;
                    s[ni][r] += emb[indices[ij] * 12 + h] + emb[indices[4096 + ij] * 12 + h]
                              + mask[widx * 4096 + ij];
                }
            }
            #pragma unroll
            for (int r = 0; r < 4; ++r){
                float mx = fmaxf(fmaxf(s[0][r], s[1][r]), fmaxf(s[2][r], s[3][r]));
                mx = fmaxf(mx, __shfl_xor(mx, 1, 64));
                mx = fmaxf(mx, __shfl_xor(mx, 2, 64));
                mx = fmaxf(mx, __shfl_xor(mx, 4, 64));
                mx = fmaxf(mx, __shfl_xor(mx, 8, 64));
                float e0 = __expf(s[0][r] - mx), e1 = __expf(s[1][r] - mx);
                float e2 = __expf(s[2][r] - mx), e3 = __expf(s[3][r] - mx);
                float sm = e0 + e1 + e2 + e3;
                sm += __shfl_xor(sm, 1, 64);
                sm += __shfl_xor(sm, 2, 64);
                sm += __shfl_xor(sm, 4, 64);
                sm += __shfl_xor(sm, 8, 64);
                float inv = 1.0f / sm;
                const int qq = mi * 16 + hi * 4 + r;
                pT[qq * 72 +  0 + lo] = f2b(e0 * inv);
                pT[qq * 72 + 16 + lo] = f2b(e1 * inv);
                pT[qq * 72 + 32 + lo] = f2b(e2 * inv);
                pT[qq * 72 + 48 + lo] = f2b(e3 * inv);
            }
        }
        __syncthreads();
        {
            const int tr = wave;
            #pragma unroll
            for (int tc = 0; tc < 2; ++tc){
                f32x4 acc = {0.f, 0.f, 0.f, 0.f};
                #pragma unroll
                for (int st = 0; st < 2; ++st){
                    bf16x8 a = *reinterpret_cast<const bf16x8*>(pT + (tr * 16 + lo) * 72 + st * 32 + hi * 8);
                    bf16x8 bb = *reinterpret_cast<const bf16x8*>(vT + (tc * 16 + lo) * 72 + st * 32 + hi * 8);
                    acc = MFMA(a, bb, acc, 0, 0, 0);
                }
                #pragma unroll
                for (int r = 0; r < 4; ++r){
                    const int token = tr * 16 + hi * 4 + r;
                    O[token * 392 + h * 32 + tc * 16 + lo] = f2b(acc[r]);
                }
            }
        }
        __syncthreads();
    }
    {
        const int tr = wave;
        bf16x8 afr[12];
        #pragma unroll
        for (int kb = 0; kb < 12; ++kb)
            afr[kb] = *reinterpret_cast<const bf16x8*>(O + (tr * 16 + lo) * 392 + kb * 32 + hi * 8);
        for (int tc = 0; tc < 24; ++tc){
            const int col = tc * 16 + lo;
            f32x4 acc = {0.f, 0.f, 0.f, 0.f};
            #pragma unroll
            for (int kb = 0; kb < 12; ++kb){
                bf16x8 bb = load_bT(wprojT, wproj, useT, col, kb * 32 + hi * 8, 384);
                acc = MFMA(afr[kb], bb, acc, 0, 0, 0);
            }
            const float bv = bproj[col];
            #pragma unroll
            for (int r = 0; r < 4; ++r){
                const int token = tr * 16 + hi * 4 + r;
                const int ih = token >> 3, iw = token & 7;
                const int gh = ((wh * 8 + ih) + 4) & 63, gw = ((wwi * 8 + iw) + 4) & 63;
                out[((size_t)b * 4096 + gh * 64 + gw) * 384 + col] = acc[r] + bv;
            }
        }
    }
}

// ---------------------------------------------------------------- launch
extern "C" void kernel_launch(void* const* d_in, const int* in_sizes, int n_in,
                              void* d_out, int out_size, void* d_ws, size_t ws_size,
                              hipStream_t stream){
    const float* x     = (const float*)d_in[0];
    const float* wqkv  = (const float*)d_in[1];
    const float* wproj = (const float*)d_in[2];
    const float* bproj = (const float*)d_in[3];
    const float* emb   = (const float*)d_in[4];
    const int*   idx   = (const int*)d_in[5];
    const float* mask  = (const float*)d_in[6];
    float* out = (float*)d_out;

    const int B = in_sizes[0] / (4096 * 384);
    const int NWIN = B * 64;

    unsigned short* ws = (unsigned short*)d_ws;
    const size_t W1 = (size_t)1152 * 384;           // wqkvP elems
    const size_t W2 = (size_t)384 * 384;            // wprojP elems
    const size_t BM = (size_t)64 * 12 * 4096;       // bm2 elems
    const size_t QE = (size_t)NWIN * 12 * 64 * 32;  // q/k/v elems each
    const size_t full_need = (W1 + W2 + BM + 3 * QE) * 2;
    const size_t mid_need  = (W1 + W2 + QE) * 2;
    const size_t low_need  = (W1 + W2) * 2;

    if (d_ws && ws_size >= full_need){
        unsigned short* wqkvP  = ws;
        unsigned short* wprojP = ws + W1;
        unsigned short* bm2    = ws + W1 + W2;
        unsigned short* qg     = bm2 + BM;
        unsigned short* kg     = qg + QE;
        unsigned short* vg     = kg + QE;
        prep_full<<<dim3(14592), dim3(256), 0, stream>>>(wqkv, wproj, emb, idx, mask,
                                                         wqkvP, wprojP, bm2);
        qkv_gemm<<<dim3(NWIN), dim3(256), 0, stream>>>(x, wqkvP, qg, kg, vg);
        // O overwrites qg in place (each wave consumes its q before writing O)
        attn_only<<<dim3(NWIN * 3), dim3(256), 0, stream>>>(qg, kg, vg, bm2, qg);
        proj_only<<<dim3(NWIN * 2), dim3(256), 0, stream>>>(qg, wprojP, bproj, out);
    } else if (d_ws && ws_size >= mid_need){
        unsigned short* wqkvT  = ws;
        unsigned short* wprojT = ws + W1;
        unsigned short* Og     = ws + W1 + W2;
        transpose_weights<<<dim3(2304), dim3(256), 0, stream>>>(wqkv, wproj, wqkvT, wprojT);
        fused_noproj<<<dim3(NWIN), dim3(256), 0, stream>>>(x, emb, idx, mask, wqkvT, Og);
        proj_gemm_T<<<dim3(NWIN), dim3(256), 0, stream>>>(Og, wprojT, bproj, out);
    } else {
        unsigned short* wqkvT  = ws;
        unsigned short* wprojT = ws ? ws + W1 : nullptr;
        const int useT = (d_ws != nullptr && ws_size >= low_need) ? 1 : 0;
        if (useT)
            transpose_weights<<<dim3(2304), dim3(256), 0, stream>>>(wqkv, wproj, wqkvT, wprojT);
        swin_attn_kernel<<<dim3(NWIN), dim3(256), 0, stream>>>(
            x, wqkv, wproj, bproj, emb, idx, mask, wqkvT, wprojT, useT, out);
    }
}

// Round 6
// 346.351 us; speedup vs baseline: 3.9362x; 1.0981x over previous
//
#include <hip/hip_runtime.h>
#include <hip/hip_bf16.h>

typedef __bf16 bf16x8 __attribute__((ext_vector_type(8)));
typedef float f32x4 __attribute__((ext_vector_type(4)));
typedef float f32x4v __attribute__((ext_vector_type(4)));
typedef unsigned short u16x8 __attribute__((ext_vector_type(8)));
typedef unsigned short u16x4 __attribute__((ext_vector_type(4)));

#define NHEADS 12
#define SCALE 0.05103103630798288f  /* 384^-0.5 */
#define MFMA __builtin_amdgcn_mfma_f32_16x16x32_bf16

static __device__ __forceinline__ unsigned short f2b(float f){
    unsigned u = __float_as_uint(f);
    unsigned r = u + 0x7FFFu + ((u >> 16) & 1u);
    return (unsigned short)(r >> 16);
}
static __device__ __forceinline__ float b2f(unsigned short u){
    union { float f; unsigned u32; } v; v.u32 = ((unsigned)u) << 16; return v.f;
}

// q/k/v global layout (per head-pair, 2048 u16): granule-permuted so BOTH the
// qkv stores (512B contiguous per instruction) and the attn fragment loads
// (16B/lane) are fully coalesced:
//   q/k (element (tok,d)):  off = (d>>4)*1024 + (tok>>4)*256 + ((d>>3)&1)*128
//                                 + (tok&15)*8 + ((d>>2)&1)*4
//   v   (element (d,tok)):  off = (d>>4)*1024 + (tok>>4)*256 + ((tok>>3)&1)*128
//                                 + (d&15)*8 + ((tok>>2)&1)*4

// ---------------------------------------------------------------- prep (FULL)
__global__ void prep_full(const float* __restrict__ wqkv, const float* __restrict__ wproj,
                          const float* __restrict__ emb, const int* __restrict__ indices,
                          const float* __restrict__ mask,
                          unsigned short* __restrict__ wqkvP,
                          unsigned short* __restrict__ wprojP,
                          unsigned short* __restrict__ bm2){
    int i = blockIdx.x * 256 + threadIdx.x;
    if (i < 442368){
        int j = i & 7, rest = i >> 3;
        int ln = rest & 63; rest >>= 6;
        int kf = rest % 12, t = rest / 12;
        int k = kf * 32 + (ln >> 4) * 8 + j;
        int col = t * 16 + (ln & 15);
        wqkvP[i] = f2b(wqkv[k * 1152 + col]);
        return;
    }
    i -= 442368;
    if (i < 147456){
        int j = i & 7, rest = i >> 3;
        int ln = rest & 63; rest >>= 6;
        int kf = rest % 12, t = rest / 12;
        int k = kf * 32 + (ln >> 4) * 8 + j;
        int col = t * 16 + (ln & 15);
        wprojP[i] = f2b(wproj[k * 384 + col]);
        return;
    }
    i -= 147456;
    if (i < 64 * 12 * 4096){
        int w = i / 49152, rem = i % 49152;
        int h = rem / 4096, r2 = rem & 4095;
        int col = r2 >> 6, row = r2 & 63;          // col=key, row=query
        int ij = row * 64 + col;
        float v = emb[indices[ij] * 12 + h] + emb[indices[4096 + ij] * 12 + h]
                + mask[w * 4096 + ij];
        bm2[i] = f2b(v);
    }
}

// ---------------------------------------------------------------- K1 (FULL)
// One window per block, EIGHT waves (512 thr). Per section each wave owns
// 3 W-tiles x all 4 token-tiles: acc[3][4]=48 VGPRs (no spill at 128 cap),
// B fragments loaded ONCE (v5's tp-split loaded them twice), A ds_reads
// 144/wave, 432 MFMAs/wave. Chip B traffic halves; 16 waves/CU (2 blocks).
// q/k: operand-swapped MFMA (d on regs, tok on lanes); v: normal. All stores
// land in the permuted layout -> every store instruction is 512B contig NT.
__global__ __launch_bounds__(512, 4) void qkv_gemm(
    const float* __restrict__ x, const unsigned short* __restrict__ wqkvP,
    unsigned short* __restrict__ qg, unsigned short* __restrict__ kg,
    unsigned short* __restrict__ vg)
{
    __shared__ unsigned short As[64 * 384];       // 48 KiB, chunk-swizzled
    const int tid = threadIdx.x, wave = tid >> 6, lane = tid & 63;
    const int lo = lane & 15, hi = lane >> 4;
    const int win = blockIdx.x;
    const int widx = win & 63, wh = widx >> 3, ww = widx & 7, b = win >> 6;

    { // stage A: 64 rows, 8 threads/row, 6 chunks of 8 bf16 each (nt f32 loads)
        const int r = tid >> 3;
        const int ih = r >> 3, iw = r & 7;
        const int gh = (wh * 8 + ih + 4) & 63, gw = (ww * 8 + iw + 4) & 63;
        const float* src = x + ((size_t)(b * 4096 + gh * 64 + gw)) * 384;
        unsigned short* dst = As + r * 384;
        const int sw = r & 7;
        #pragma unroll
        for (int i = 0; i < 6; ++i){
            const int c = (tid & 7) + i * 8;
            f32x4v f0 = __builtin_nontemporal_load(
                reinterpret_cast<const f32x4v*>(src + c * 8));
            f32x4v f1 = __builtin_nontemporal_load(
                reinterpret_cast<const f32x4v*>(src + c * 8 + 4));
            union { bf16x8 v; unsigned short s[8]; } u;
            u.s[0]=f2b(f0[0]); u.s[1]=f2b(f0[1]); u.s[2]=f2b(f0[2]); u.s[3]=f2b(f0[3]);
            u.s[4]=f2b(f1[0]); u.s[5]=f2b(f1[1]); u.s[6]=f2b(f1[2]); u.s[7]=f2b(f1[3]);
            const int cs = (c & ~7) | ((c & 7) ^ sw);
            *reinterpret_cast<bf16x8*>(dst + cs * 8) = u.v;
        }
    }
    __syncthreads();

    #pragma unroll 1
    for (int sec = 0; sec < 3; ++sec){
        const int g0 = wave * 3;                   // first col-tile within section
        const unsigned short* bp = wqkvP + (size_t)(sec * 24 + g0) * 12 * 512 + lane * 8;
        const float sc = (sec == 0) ? SCALE : 1.0f;
        unsigned short* basep = (sec == 0 ? qg : sec == 1 ? kg : vg);

        f32x4 acc[3][4];
        #pragma unroll
        for (int wt = 0; wt < 3; ++wt)
            #pragma unroll
            for (int tt = 0; tt < 4; ++tt) acc[wt][tt] = {0,0,0,0};

        #pragma unroll 2
        for (int kf = 0; kf < 12; ++kf){
            bf16x8 bw[3];
            #pragma unroll
            for (int wt = 0; wt < 3; ++wt)
                bw[wt] = *reinterpret_cast<const bf16x8*>(bp + (wt * 12 + kf) * 512);
            const int c = kf * 4 + hi;
            if (sec < 2){
                #pragma unroll
                for (int tt = 0; tt < 4; ++tt){
                    const int r = tt * 16 + lo;
                    const int cs = (c & ~7) | ((c & 7) ^ (r & 7));
                    bf16x8 af = *reinterpret_cast<const bf16x8*>(As + r * 384 + cs * 8);
                    #pragma unroll
                    for (int wt = 0; wt < 3; ++wt)
                        acc[wt][tt] = MFMA(bw[wt], af, acc[wt][tt], 0, 0, 0);
                }
            } else {
                #pragma unroll
                for (int tt = 0; tt < 4; ++tt){
                    const int r = tt * 16 + lo;
                    const int cs = (c & ~7) | ((c & 7) ^ (r & 7));
                    bf16x8 af = *reinterpret_cast<const bf16x8*>(As + r * 384 + cs * 8);
                    #pragma unroll
                    for (int wt = 0; wt < 3; ++wt)
                        acc[wt][tt] = MFMA(af, bw[wt], acc[wt][tt], 0, 0, 0);
                }
            }
        }

        // epilogue: permuted layout; each (wt,tt) store op = 512B contiguous
        #pragma unroll
        for (int wt = 0; wt < 3; ++wt){
            const int g = g0 + wt;                 // col-tile 0..23
            const int hloc = g >> 1, db = g & 1;
            unsigned short* dst = basep + (size_t)(win * 12 + hloc) * 2048
                                + db * 1024 + (hi >> 1) * 128 + lo * 8 + (hi & 1) * 4;
            #pragma unroll
            for (int tt = 0; tt < 4; ++tt){
                u16x4 u;
                u[0] = f2b(acc[wt][tt][0] * sc); u[1] = f2b(acc[wt][tt][1] * sc);
                u[2] = f2b(acc[wt][tt][2] * sc); u[3] = f2b(acc[wt][tt][3] * sc);
                __builtin_nontemporal_store(u, reinterpret_cast<u16x4*>(dst + tt * 256));
            }
        }
    }
}

// ---------------------------------------------------------------- K2a (FULL)
// Attention only. One (window, 4-head group) per block, one head per wave.
// Fragment loads use the granule-permuted q/k/v layout (see top).
// O written bf16 head-major [pair][tok][32] IN PLACE over qg (normal stores).
__global__ __launch_bounds__(256, 4) void attn_only(
    const unsigned short* __restrict__ qg, const unsigned short* __restrict__ kg,
    const unsigned short* __restrict__ vg, const unsigned short* __restrict__ bm2,
    unsigned short* __restrict__ Og)
{
    __shared__ unsigned short psm_all[4][64 * 64];   // 32 KiB, XOR-swizzled
    __shared__ unsigned short tb_all[4][512];        // 4 KiB transpose bounce
    const int tid = threadIdx.x, wave = tid >> 6, lane = tid & 63;
    const int lo = lane & 15, hi = lane >> 4;
    const int bid = blockIdx.x;
    const int win = bid / 3, e = bid - win * 3;
    const int widx = win & 63;
    const int h = e * 4 + wave;
    const size_t pair = (size_t)(win * 12 + h);
    const unsigned short* qb  = qg + pair * 2048;
    const unsigned short* kbp = kg + pair * 2048;
    const unsigned short* vb  = vg + pair * 2048;
    const unsigned short* bmb = bm2 + (size_t)(widx * 12 + h) * 4096;
    unsigned short* psm = psm_all[wave];
    const int fbase = (hi >> 1) * 1024 + (hi & 1) * 128 + lo * 8;  // q/k frag base

    bf16x8 kf[4];
    #pragma unroll
    for (int ct = 0; ct < 4; ++ct)
        kf[ct] = *reinterpret_cast<const bf16x8*>(kbp + fbase + ct * 256);

    #pragma unroll
    for (int rh = 0; rh < 2; ++rh){
        f32x4 s[2][4];
        __builtin_amdgcn_s_setprio(1);
        #pragma unroll
        for (int rt2 = 0; rt2 < 2; ++rt2){
            bf16x8 qf = *reinterpret_cast<const bf16x8*>(
                qb + fbase + (rh * 2 + rt2) * 256);
            #pragma unroll
            for (int ct = 0; ct < 4; ++ct){
                f32x4 z = {0,0,0,0};
                s[rt2][ct] = MFMA(qf, kf[ct], z, 0, 0, 0);
            }
        }
        __builtin_amdgcn_s_setprio(0);
        #pragma unroll
        for (int rt2 = 0; rt2 < 2; ++rt2)
            #pragma unroll
            for (int ct = 0; ct < 4; ++ct){
                ushort4 bv = *reinterpret_cast<const ushort4*>(
                    bmb + (ct * 16 + lo) * 64 + (rh * 2 + rt2) * 16 + hi * 4);
                s[rt2][ct][0] += b2f(bv.x);
                s[rt2][ct][1] += b2f(bv.y);
                s[rt2][ct][2] += b2f(bv.z);
                s[rt2][ct][3] += b2f(bv.w);
            }
        #pragma unroll
        for (int rt2 = 0; rt2 < 2; ++rt2)
            #pragma unroll
            for (int r4 = 0; r4 < 4; ++r4){
                float mx = fmaxf(fmaxf(s[rt2][0][r4], s[rt2][1][r4]),
                                 fmaxf(s[rt2][2][r4], s[rt2][3][r4]));
                mx = fmaxf(mx, __shfl_xor(mx, 1, 64));
                mx = fmaxf(mx, __shfl_xor(mx, 2, 64));
                mx = fmaxf(mx, __shfl_xor(mx, 4, 64));
                mx = fmaxf(mx, __shfl_xor(mx, 8, 64));
                float e0 = __expf(s[rt2][0][r4] - mx), e1 = __expf(s[rt2][1][r4] - mx);
                float e2 = __expf(s[rt2][2][r4] - mx), e3 = __expf(s[rt2][3][r4] - mx);
                float sm = e0 + e1 + e2 + e3;
                sm += __shfl_xor(sm, 1, 64);
                sm += __shfl_xor(sm, 2, 64);
                sm += __shfl_xor(sm, 4, 64);
                sm += __shfl_xor(sm, 8, 64);
                const float inv = 1.0f / sm;
                const int row = (rh * 2 + rt2) * 16 + hi * 4 + r4;
                const int rsw = row & 7;
                #pragma unroll
                for (int ct = 0; ct < 4; ++ct){
                    const int c = ct * 2 + (lo >> 3);
                    const float ev = (ct == 0 ? e0 : ct == 1 ? e1 : ct == 2 ? e2 : e3);
                    psm[row * 64 + (c ^ rsw) * 8 + (lo & 7)] = f2b(ev * inv);
                }
            }
    }
    asm volatile("" ::: "memory");

    f32x4 o[4][2];
    #pragma unroll
    for (int rt = 0; rt < 4; ++rt){ o[rt][0] = {0,0,0,0}; o[rt][1] = {0,0,0,0}; }
    #pragma unroll
    for (int ks = 0; ks < 2; ++ks){
        bf16x8 vf[2];
        #pragma unroll
        for (int ct2 = 0; ct2 < 2; ++ct2)
            vf[ct2] = *reinterpret_cast<const bf16x8*>(
                vb + ct2 * 1024 + (ks * 2 + (hi >> 1)) * 256 + (hi & 1) * 128 + lo * 8);
        __builtin_amdgcn_s_setprio(1);
        #pragma unroll
        for (int rt = 0; rt < 4; ++rt){
            const int row = rt * 16 + lo;
            const int c = ks * 4 + hi;
            bf16x8 pa = *reinterpret_cast<const bf16x8*>(
                psm + row * 64 + (c ^ (row & 7)) * 8);
            o[rt][0] = MFMA(pa, vf[0], o[rt][0], 0, 0, 0);
            o[rt][1] = MFMA(pa, vf[1], o[rt][1], 0, 0, 0);
        }
        __builtin_amdgcn_s_setprio(0);
    }

    // O epilogue: C-layout -> [tok][32] via LDS bounce -> 1KB coalesced store.
    // NORMAL store (cached): proj_only reads this back immediately.
    unsigned short* tb = tb_all[wave];
    #pragma unroll
    for (int rt = 0; rt < 4; ++rt){
        asm volatile("" ::: "memory");
        #pragma unroll
        for (int ct2 = 0; ct2 < 2; ++ct2)
            #pragma unroll
            for (int r4 = 0; r4 < 4; ++r4)
                tb[(hi * 4 + r4) * 32 + ct2 * 16 + lo] = f2b(o[rt][ct2][r4]);
        asm volatile("" ::: "memory");
        u16x8 v = *reinterpret_cast<const u16x8*>(tb + (lane >> 2) * 32 + (lane & 3) * 8);
        *reinterpret_cast<u16x8*>(
            Og + pair * 2048 + rt * 512 + (lane >> 2) * 32 + (lane & 3) * 8) = v;
        asm volatile("" ::: "memory");
    }
}

// ---------------------------------------------------------------- K2b (FULL)
// Proj GEMM. HALF-window per block (32 tokens): LDS 24.5K. Stage O (head-major
// bf16, L2-hot) into swizzled As; packed-B GEMM; epilogue bounces f32 through
// LDS so stores are FULL-LINE nontemporal row writes.
__global__ __launch_bounds__(256, 4) void proj_only(
    const unsigned short* __restrict__ Og, const unsigned short* __restrict__ wprojP,
    const float* __restrict__ bproj, float* __restrict__ out)
{
    __shared__ __attribute__((aligned(16))) unsigned char smem[25088];
    unsigned short* As = reinterpret_cast<unsigned short*>(smem);  // 32x384 bf16 swz
    float* Asf = reinterpret_cast<float*>(smem);                   // 16x392 f32 bounce
    const int tid = threadIdx.x, wave = tid >> 6, lane = tid & 63;
    const int lo = lane & 15, hi = lane >> 4;
    const int blk = blockIdx.x;
    const int win = blk >> 1, half = blk & 1;
    const int widx = win & 63, wh = widx >> 3, ww = widx & 7, b = win >> 6;

    { // stage 32 tokens x 384 cols; col chunk c -> head c>>2, sub-chunk c&3
        const int r = tid >> 3;              // local row 0..31
        const int c0 = tid & 7;
        const int tokg = half * 32 + r;
        #pragma unroll
        for (int i = 0; i < 6; ++i){
            const int c = c0 + i * 8;        // chunk 0..47
            const int h = c >> 2;
            bf16x8 v = *reinterpret_cast<const bf16x8*>(
                Og + (size_t)(win * 12 + h) * 2048 + tokg * 32 + (c & 3) * 8);
            const int cs = (c & ~7) | ((c & 7) ^ (r & 7));
            *reinterpret_cast<bf16x8*>(As + r * 384 + cs * 8) = v;
        }
    }
    __syncthreads();

    // GEMM: wave owns 96 output cols (6 tiles); 2 row-tiles (32 tokens)
    f32x4 acc[2][6];
    #pragma unroll
    for (int rt = 0; rt < 2; ++rt)
        #pragma unroll
        for (int ct = 0; ct < 6; ++ct) acc[rt][ct] = {0,0,0,0};
    #pragma unroll
    for (int kf = 0; kf < 12; ++kf){
        bf16x8 bfr[6];
        #pragma unroll
        for (int ct = 0; ct < 6; ++ct){
            const int t = wave * 6 + ct;
            bfr[ct] = *reinterpret_cast<const bf16x8*>(
                wprojP + (size_t)(t * 12 + kf) * 512 + lane * 8);
        }
        const int c = kf * 4 + hi;
        #pragma unroll
        for (int rt = 0; rt < 2; ++rt){
            const int r = rt * 16 + lo;
            const int cs = (c & ~7) | ((c & 7) ^ (r & 7));
            bf16x8 af = *reinterpret_cast<const bf16x8*>(As + r * 384 + cs * 8);
            #pragma unroll
            for (int ct = 0; ct < 6; ++ct)
                acc[rt][ct] = MFMA(af, bfr[ct], acc[rt][ct], 0, 0, 0);
        }
    }

    // epilogue: two 16-token rounds through f32 LDS -> full-row nt stores
    #pragma unroll
    for (int p = 0; p < 2; ++p){
        __syncthreads();
        #pragma unroll
        for (int ct = 0; ct < 6; ++ct){
            const int col = wave * 96 + ct * 16 + lo;
            const float bv = bproj[col];
            #pragma unroll
            for (int r4 = 0; r4 < 4; ++r4)
                Asf[(hi * 4 + r4) * 392 + col] = acc[p][ct][r4] + bv;
        }
        __syncthreads();
        const int row = tid >> 4, tcol = tid & 15;
        const int tok = half * 32 + p * 16 + row;
        const int ih = tok >> 3, iw = tok & 7;
        const int gh = (wh * 8 + ih + 4) & 63, gw = (ww * 8 + iw + 4) & 63;
        float* orow = out + ((size_t)(b * 4096 + gh * 64 + gw)) * 384;
        #pragma unroll
        for (int j = 0; j < 6; ++j){
            f32x4 v = *reinterpret_cast<const f32x4*>(Asf + row * 392 + j * 64 + tcol * 4);
            __builtin_nontemporal_store(v, reinterpret_cast<f32x4*>(orow + j * 64 + tcol * 4));
        }
    }
}

// ---------------------------------------------------------------- prep (MID/LOW)
__global__ void transpose_weights(const float* __restrict__ wqkv,
                                  const float* __restrict__ wproj,
                                  unsigned short* __restrict__ wqkvT,
                                  unsigned short* __restrict__ wprojT){
    int i = blockIdx.x * 256 + threadIdx.x;
    if (i < 1152 * 384){ int j = i / 384, k = i % 384; wqkvT[i] = f2b(wqkv[k * 1152 + j]); }
    i -= 1152 * 384;
    if (i >= 0 && i < 384 * 384){ int j = i / 384, k = i % 384; wprojT[i] = f2b(wproj[k * 384 + j]); }
}

// ---------------------------------------------------------------- MID fused (no proj)
__global__ __launch_bounds__(256) void fused_noproj(
    const float* __restrict__ x, const float* __restrict__ emb,
    const int* __restrict__ indices, const float* __restrict__ mask,
    const unsigned short* __restrict__ wqkvT, unsigned short* __restrict__ Og)
{
    __shared__ unsigned short smem[37120];
    unsigned short* xw = smem;
    unsigned short* qT = smem + 25088;
    unsigned short* kT = smem + 27648;
    unsigned short* vT = smem + 30208;
    unsigned short* pT = smem + 32512;

    const int tid = threadIdx.x, wave = tid >> 6, lane = tid & 63;
    const int lo = lane & 15, hi = lane >> 4;
    const int blk = blockIdx.x, b = blk >> 6, widx = blk & 63;
    const int wh = widx >> 3, wwi = widx & 7;

    {
        const int n = tid >> 2, qp = tid & 3;
        const int ih = n >> 3, iw = n & 7;
        const int gh = ((wh * 8 + ih) + 4) & 63, gw = ((wwi * 8 + iw) + 4) & 63;
        const size_t src = ((size_t)b * 4096 + gh * 64 + gw) * 384 + qp * 96;
        const float4* gp = reinterpret_cast<const float4*>(x + src);
        unsigned short* dst = xw + n * 392 + qp * 96;
        #pragma unroll
        for (int i = 0; i < 24; ++i){
            float4 f = gp[i];
            ushort4 u;
            u.x = f2b(f.x); u.y = f2b(f.y); u.z = f2b(f.z); u.w = f2b(f.w);
            *reinterpret_cast<ushort4*>(dst + i * 4) = u;
        }
    }
    __syncthreads();

    for (int h = 0; h < NHEADS; ++h){
        #pragma unroll
        for (int j = 0; j < 6; ++j){
            const int t = wave * 6 + j;
            const int m = t >> 3, tt = t & 7;
            const int tr = tt >> 1, tc = tt & 1;
            const int col = m * 384 + h * 32 + tc * 16 + lo;
            f32x4 acc = {0.f, 0.f, 0.f, 0.f};
            #pragma unroll
            for (int kb = 0; kb < 12; ++kb){
                bf16x8 a = *reinterpret_cast<const bf16x8*>(xw + (tr * 16 + lo) * 392 + kb * 32 + hi * 8);
                bf16x8 bb = *reinterpret_cast<const bf16x8*>(wqkvT + (size_t)col * 384 + kb * 32 + hi * 8);
                acc = MFMA(a, bb, acc, 0, 0, 0);
            }
            #pragma unroll
            for (int r = 0; r < 4; ++r){
                const int token = tr * 16 + hi * 4 + r;
                const int d = tc * 16 + lo;
                if (m == 0)      qT[token * 40 + d] = f2b(acc[r] * SCALE);
                else if (m == 1) kT[token * 40 + d] = f2b(acc[r]);
                else             vT[d * 72 + token] = f2b(acc[r]);
            }
        }
        __syncthreads();
        {
            const int mi = wave;
            bf16x8 qf = *reinterpret_cast<const bf16x8*>(qT + (mi * 16 + lo) * 40 + hi * 8);
            f32x4 s[4];
            #pragma unroll
            for (int ni = 0; ni < 4; ++ni){
                bf16x8 kfr = *reinterpret_cast<const bf16x8*>(kT + (ni * 16 + lo) * 40 + hi * 8);
                f32x4 z = {0.f, 0.f, 0.f, 0.f};
                s[ni] = MFMA(qf, kfr, z, 0, 0, 0);
            }
            #pragma unroll
            for (int ni = 0; ni < 4; ++ni){
                const int kk = ni * 16 + lo;
                #pragma unroll
                for (int r = 0; r < 4; ++r){
                    const int qq = mi * 16 + hi * 4 + r;
                    const int ij = qq * 64 + kk;
                    s[ni][r] += emb[indices[ij] * 12 + h] + emb[indices[4096 + ij] * 12 + h]
                              + mask[widx * 4096 + ij];
                }
            }
            #pragma unroll
            for (int r = 0; r < 4; ++r){
                float mx = fmaxf(fmaxf(s[0][r], s[1][r]), fmaxf(s[2][r], s[3][r]));
                mx = fmaxf(mx, __shfl_xor(mx, 1, 64));
                mx = fmaxf(mx, __shfl_xor(mx, 2, 64));
                mx = fmaxf(mx, __shfl_xor(mx, 4, 64));
                mx = fmaxf(mx, __shfl_xor(mx, 8, 64));
                float e0 = __expf(s[0][r] - mx), e1 = __expf(s[1][r] - mx);
                float e2 = __expf(s[2][r] - mx), e3 = __expf(s[3][r] - mx);
                float sm = e0 + e1 + e2 + e3;
                sm += __shfl_xor(sm, 1, 64);
                sm += __shfl_xor(sm, 2, 64);
                sm += __shfl_xor(sm, 4, 64);
                sm += __shfl_xor(sm, 8, 64);
                float inv = 1.0f / sm;
                const int qq = mi * 16 + hi * 4 + r;
                pT[qq * 72 +  0 + lo] = f2b(e0 * inv);
                pT[qq * 72 + 16 + lo] = f2b(e1 * inv);
                pT[qq * 72 + 32 + lo] = f2b(e2 * inv);
                pT[qq * 72 + 48 + lo] = f2b(e3 * inv);
            }
        }
        __syncthreads();
        {
            const int tr = wave;
            #pragma unroll
            for (int tc = 0; tc < 2; ++tc){
                f32x4 acc = {0.f, 0.f, 0.f, 0.f};
                #pragma unroll
                for (int st = 0; st < 2; ++st){
                    bf16x8 a = *reinterpret_cast<const bf16x8*>(pT + (tr * 16 + lo) * 72 + st * 32 + hi * 8);
                    bf16x8 bb = *reinterpret_cast<const bf16x8*>(vT + (tc * 16 + lo) * 72 + st * 32 + hi * 8);
                    acc = MFMA(a, bb, acc, 0, 0, 0);
                }
                #pragma unroll
                for (int r = 0; r < 4; ++r){
                    const int token = tr * 16 + hi * 4 + r;
                    Og[((size_t)blk * 64 + token) * 384 + h * 32 + tc * 16 + lo] = f2b(acc[r]);
                }
            }
        }
        __syncthreads();
    }
}

// ---------------------------------------------------------------- MID proj
__global__ __launch_bounds__(256) void proj_gemm_T(
    const unsigned short* __restrict__ Og, const unsigned short* __restrict__ wprojT,
    const float* __restrict__ bproj, float* __restrict__ out)
{
    __shared__ unsigned short As[64 * 384];
    const int tid = threadIdx.x, wave = tid >> 6, lane = tid & 63;
    const int lo = lane & 15, hi = lane >> 4;
    const int win = blockIdx.x;
    const int widx = win & 63, wh = widx >> 3, ww = widx & 7, b = win >> 6;

    {
        const int r = tid >> 2;
        const unsigned short* src = Og + ((size_t)win * 64 + r) * 384;
        const int sw = r & 7;
        #pragma unroll
        for (int i = 0; i < 12; ++i){
            const int c = (tid & 3) + i * 4;
            bf16x8 v = *reinterpret_cast<const bf16x8*>(src + c * 8);
            const int cs = (c & ~7) | ((c & 7) ^ sw);
            *reinterpret_cast<bf16x8*>(As + r * 384 + cs * 8) = v;
        }
    }
    __syncthreads();

    #pragma unroll 1
    for (int nc = 0; nc < 3; ++nc){
        f32x4 acc[4][2];
        #pragma unroll
        for (int rt = 0; rt < 4; ++rt){ acc[rt][0] = {0,0,0,0}; acc[rt][1] = {0,0,0,0}; }
        #pragma unroll
        for (int kb = 0; kb < 6; ++kb){
            bf16x8 bf[2][2];
            #pragma unroll
            for (int ct = 0; ct < 2; ++ct)
                #pragma unroll
                for (int ks = 0; ks < 2; ++ks){
                    const int col = nc * 128 + wave * 32 + ct * 16 + lo;
                    bf[ct][ks] = *reinterpret_cast<const bf16x8*>(
                        wprojT + (size_t)col * 384 + kb * 64 + ks * 32 + hi * 8);
                }
            #pragma unroll
            for (int ks = 0; ks < 2; ++ks)
                #pragma unroll
                for (int rt = 0; rt < 4; ++rt){
                    const int r = rt * 16 + lo;
                    const int c = kb * 8 + ks * 4 + hi;
                    const int cs = (c & ~7) | ((c & 7) ^ (r & 7));
                    bf16x8 af = *reinterpret_cast<const bf16x8*>(As + r * 384 + cs * 8);
                    acc[rt][0] = MFMA(af, bf[0][ks], acc[rt][0], 0, 0, 0);
                    acc[rt][1] = MFMA(af, bf[1][ks], acc[rt][1], 0, 0, 0);
                }
        }
        #pragma unroll
        for (int rt = 0; rt < 4; ++rt)
            #pragma unroll
            for (int ct = 0; ct < 2; ++ct){
                const int col = nc * 128 + wave * 32 + ct * 16 + lo;
                const float bv = bproj[col];
                #pragma unroll
                for (int r4 = 0; r4 < 4; ++r4){
                    const int tok = rt * 16 + hi * 4 + r4;
                    const int ih = tok >> 3, iw = tok & 7;
                    const int gh = (wh * 8 + ih + 4) & 63, gw = (ww * 8 + iw + 4) & 63;
                    out[((size_t)(b * 4096 + gh * 64 + gw)) * 384 + col] =
                        acc[rt][ct][r4] + bv;
                }
            }
    }
}

// ---------------------------------------------------------------- LOW fallback
static __device__ __forceinline__ bf16x8 load_bT(const unsigned short* __restrict__ WT,
                                                 const float* __restrict__ Worig,
                                                 int useT, int col, int k0, int ldOrig){
    if (useT){
        return *reinterpret_cast<const bf16x8*>(WT + (size_t)col * 384 + k0);
    } else {
        union { bf16x8 v; unsigned short s[8]; } u;
        #pragma unroll
        for (int i = 0; i < 8; ++i) u.s[i] = f2b(Worig[(size_t)(k0 + i) * ldOrig + col]);
        return u.v;
    }
}

__global__ __launch_bounds__(256) void swin_attn_kernel(
    const float* __restrict__ x, const float* __restrict__ wqkv,
    const float* __restrict__ wproj, const float* __restrict__ bproj,
    const float* __restrict__ emb, const int* __restrict__ indices,
    const float* __restrict__ mask, const unsigned short* __restrict__ wqkvT,
    const unsigned short* __restrict__ wprojT, int useT, float* __restrict__ out)
{
    __shared__ unsigned short smem[62208];
    unsigned short* xw = smem;
    unsigned short* O  = smem + 25088;
    unsigned short* qT = smem + 50176;
    unsigned short* kT = smem + 52736;
    unsigned short* vT = smem + 55296;
    unsigned short* pT = smem + 57600;

    const int tid = threadIdx.x, wave = tid >> 6, lane = tid & 63;
    const int lo = lane & 15, hi = lane >> 4;
    const int blk = blockIdx.x, b = blk >> 6, widx = blk & 63;
    const int wh = widx >> 3, wwi = widx & 7;

    {
        const int n = tid >> 2, qp = tid & 3;
        const int ih = n >> 3, iw = n & 7;
        const int gh = ((wh * 8 + ih) + 4) & 63, gw = ((wwi * 8 + iw) + 4) & 63;
        const size_t src = ((size_t)b * 4096 + gh * 64 + gw) * 384 + qp * 96;
        const float4* gp = reinterpret_cast<const float4*>(x + src);
        unsigned short* dst = xw + n * 392 + qp * 96;
        #pragma unroll
        for (int i = 0; i < 24; ++i){
            float4 f = gp[i];
            ushort4 u;
            u.x = f2b(f.x); u.y = f2b(f.y); u.z = f2b(f.z); u.w = f2b(f.w);
            *reinterpret_cast<ushort4*>(dst + i * 4) = u;
        }
    }
    __syncthreads();

    for (int h = 0; h < NHEADS; ++h){
        #pragma unroll
        for (int j = 0; j < 6; ++j){
            const int t = wave * 6 + j;
            const int m = t >> 3, tt = t & 7;
            const int tr = tt >> 1, tc = tt & 1;
            const int col = m * 384 + h * 32 + tc * 16 + lo;
            f32x4 acc = {0.f, 0.f, 0.f, 0.f};
            #pragma unroll
            for (int kb = 0; kb < 12; ++kb){
                bf16x8 a = *reinterpret_cast<const bf16x8*>(xw + (tr * 16 + lo) * 392 + kb * 32 + hi * 8);
                bf16x8 bb = load_bT(wqkvT, wqkv, useT, col, kb * 32 + hi * 8, 1152);
                acc = MFMA(a, bb, acc, 0, 0, 0);
            }
            #pragma unroll
            for (int r = 0; r < 4; ++r){
                const int token = tr * 16 + hi * 4 + r;
                const int d = tc * 16 + lo;
                if (m == 0)      qT[token * 40 + d] = f2b(acc[r] * SCALE);
                else if (m == 1) kT[token * 40 + d] = f2b(acc[r]);
                else             vT[d * 72 + token] = f2b(acc[r]);
            }
        }
        __syncthreads();
        {
            const int mi = wave;
            bf16x8 qf = *reinterpret_cast<const bf16x8*>(qT + (mi * 16 + lo) * 40 + hi * 8);
            f32x4 s[4];
            #pragma unroll
            for (int ni = 0; ni < 4; ++ni){
                bf16x8 kfr = *reinterpret_cast<const bf16x8*>(kT + (ni * 16 + lo) * 40 + hi * 8);
                f32x4 z = {0.f, 0.f, 0.f, 0.f};
                s[ni] = MFMA(qf, kfr, z, 0, 0, 0);
            }
            #pragma unroll
            for (int ni = 0; ni < 4; ++ni){
                const int kk = ni * 16 + lo;
                #pragma unroll
                for (int r = 0; r < 4; ++r){
                    const int qq = mi * 16 + hi * 4 + r;
                    const int ij = qq * 64 + kk;
                    s[ni][r] += emb[indices[ij] * 12 + h] + emb[indices[4096 + ij] * 12 + h]
                              + mask[widx * 4096 + ij];
                }
            }
            #pragma unroll
            for (int r = 0; r < 4; ++r){
                float mx = fmaxf(fmaxf(s[0][r], s[1][r]), fmaxf(s[2][r], s[3][r]));
                mx = fmaxf(mx, __shfl_xor(mx, 1, 64));
                mx = fmaxf(mx, __shfl_xor(mx, 2, 64));
                mx = fmaxf(mx, __shfl_xor(mx, 4, 64));
                mx = fmaxf(mx, __shfl_xor(mx, 8, 64));
                float e0 = __expf(s[0][r] - mx), e1 = __expf(s[1][r] - mx);
                float e2 = __expf(s[2][r] - mx), e3 = __expf(s[3][r] - mx);
                float sm = e0 + e1 + e2 + e3;
                sm += __shfl_xor(sm, 1, 64);
                sm += __shfl_xor(sm, 2, 64);
                sm += __shfl_xor(sm, 4, 64);
                sm += __shfl_xor(sm, 8, 64);
                float inv = 1.0f / sm;
                const int qq = mi * 16 + hi * 4 + r;
                pT[qq * 72 +  0 + lo] = f2b(e0 * inv);
                pT[qq * 72 + 16 + lo] = f2b(e1 * inv);
                pT[qq * 72 + 32 + lo] = f2b(e2 * inv);
                pT[qq * 72 + 48 + lo] = f2b(e3 * inv);
            }
        }
        __syncthreads();
        {
            const int tr = wave;
            #pragma unroll
            for (int tc = 0; tc < 2; ++tc){
                f32x4 acc = {0.f, 0.f, 0.f, 0.f};
                #pragma unroll
                for (int st = 0; st < 2; ++st){
                    bf16x8 a = *reinterpret_cast<const bf16x8*>(pT + (tr * 16 + lo) * 72 + st * 32 + hi * 8);
                    bf16x8 bb = *reinterpret_cast<const bf16x8*>(vT + (tc * 16 + lo) * 72 + st * 32 + hi * 8);
                    acc = MFMA(a, bb, acc, 0, 0, 0);
                }
                #pragma unroll
                for (int r = 0; r < 4; ++r){
                    const int token = tr * 16 + hi * 4 + r;
                    O[token * 392 + h * 32 + tc * 16 + lo] = f2b(acc[r]);
                }
            }
        }
        __syncthreads();
    }
    {
        const int tr = wave;
        bf16x8 afr[12];
        #pragma unroll
        for (int kb = 0; kb < 12; ++kb)
            afr[kb] = *reinterpret_cast<const bf16x8*>(O + (tr * 16 + lo) * 392 + kb * 32 + hi * 8);
        for (int tc = 0; tc < 24; ++tc){
            const int col = tc * 16 + lo;
            f32x4 acc = {0.f, 0.f, 0.f, 0.f};
            #pragma unroll
            for (int kb = 0; kb < 12; ++kb){
                bf16x8 bb = load_bT(wprojT, wproj, useT, col, kb * 32 + hi * 8, 384);
                acc = MFMA(afr[kb], bb, acc, 0, 0, 0);
            }
            const float bv = bproj[col];
            #pragma unroll
            for (int r = 0; r < 4; ++r){
                const int token = tr * 16 + hi * 4 + r;
                const int ih = token >> 3, iw = token & 7;
                const int gh = ((wh * 8 + ih) + 4) & 63, gw = ((wwi * 8 + iw) + 4) & 63;
                out[((size_t)b * 4096 + gh * 64 + gw) * 384 + col] = acc[r] + bv;
            }
        }
    }
}

// ---------------------------------------------------------------- launch
extern "C" void kernel_launch(void* const* d_in, const int* in_sizes, int n_in,
                              void* d_out, int out_size, void* d_ws, size_t ws_size,
                              hipStream_t stream){
    const float* x     = (const float*)d_in[0];
    const float* wqkv  = (const float*)d_in[1];
    const float* wproj = (const float*)d_in[2];
    const float* bproj = (const float*)d_in[3];
    const float* emb   = (const float*)d_in[4];
    const int*   idx   = (const int*)d_in[5];
    const float* mask  = (const float*)d_in[6];
    float* out = (float*)d_out;

    const int B = in_sizes[0] / (4096 * 384);
    const int NWIN = B * 64;

    unsigned short* ws = (unsigned short*)d_ws;
    const size_t W1 = (size_t)1152 * 384;           // wqkvP elems
    const size_t W2 = (size_t)384 * 384;            // wprojP elems
    const size_t BM = (size_t)64 * 12 * 4096;       // bm2 elems
    const size_t QE = (size_t)NWIN * 12 * 64 * 32;  // q/k/v elems each
    const size_t full_need = (W1 + W2 + BM + 3 * QE) * 2;
    const size_t mid_need  = (W1 + W2 + QE) * 2;
    const size_t low_need  = (W1 + W2) * 2;

    if (d_ws && ws_size >= full_need){
        unsigned short* wqkvP  = ws;
        unsigned short* wprojP = ws + W1;
        unsigned short* bm2    = ws + W1 + W2;
        unsigned short* qg     = bm2 + BM;
        unsigned short* kg     = qg + QE;
        unsigned short* vg     = kg + QE;
        prep_full<<<dim3(14592), dim3(256), 0, stream>>>(wqkv, wproj, emb, idx, mask,
                                                         wqkvP, wprojP, bm2);
        qkv_gemm<<<dim3(NWIN), dim3(512), 0, stream>>>(x, wqkvP, qg, kg, vg);
        // O overwrites qg in place (each wave consumes its q before writing O)
        attn_only<<<dim3(NWIN * 3), dim3(256), 0, stream>>>(qg, kg, vg, bm2, qg);
        proj_only<<<dim3(NWIN * 2), dim3(256), 0, stream>>>(qg, wprojP, bproj, out);
    } else if (d_ws && ws_size >= mid_need){
        unsigned short* wqkvT  = ws;
        unsigned short* wprojT = ws + W1;
        unsigned short* Og     = ws + W1 + W2;
        transpose_weights<<<dim3(2304), dim3(256), 0, stream>>>(wqkv, wproj, wqkvT, wprojT);
        fused_noproj<<<dim3(NWIN), dim3(256), 0, stream>>>(x, emb, idx, mask, wqkvT, Og);
        proj_gemm_T<<<dim3(NWIN), dim3(256), 0, stream>>>(Og, wprojT, bproj, out);
    } else {
        unsigned short* wqkvT  = ws;
        unsigned short* wprojT = ws ? ws + W1 : nullptr;
        const int useT = (d_ws != nullptr && ws_size >= low_need) ? 1 : 0;
        if (useT)
            transpose_weights<<<dim3(2304), dim3(256), 0, stream>>>(wqkv, wproj, wqkvT, wprojT);
        swin_attn_kernel<<<dim3(NWIN), dim3(256), 0, stream>>>(
            x, wqkv, wproj, bproj, emb, idx, mask, wqkvT, wprojT, useT, out);
    }
}

// Round 7
// 339.582 us; speedup vs baseline: 4.0146x; 1.0199x over previous
//
#include <hip/hip_runtime.h>
#include <hip/hip_bf16.h>

typedef __bf16 bf16x8 __attribute__((ext_vector_type(8)));
typedef float f32x4 __attribute__((ext_vector_type(4)));
typedef float f32x4v __attribute__((ext_vector_type(4)));
typedef unsigned short u16x8 __attribute__((ext_vector_type(8)));
typedef unsigned short u16x4 __attribute__((ext_vector_type(4)));

#define NHEADS 12
#define SCALE 0.05103103630798288f  /* 384^-0.5 */
#define MFMA __builtin_amdgcn_mfma_f32_16x16x32_bf16

static __device__ __forceinline__ unsigned short f2b(float f){
    unsigned u = __float_as_uint(f);
    unsigned r = u + 0x7FFFu + ((u >> 16) & 1u);
    return (unsigned short)(r >> 16);
}
static __device__ __forceinline__ float b2f(unsigned short u){
    union { float f; unsigned u32; } v; v.u32 = ((unsigned)u) << 16; return v.f;
}

// q/k/v global layout (per head-pair, 2048 u16): granule-permuted so BOTH the
// qkv stores (512B contiguous per instruction) and the attn fragment loads
// (16B/lane) are fully coalesced:
//   q/k (element (tok,d)):  off = (d>>4)*1024 + (tok>>4)*256 + ((d>>3)&1)*128
//                                 + (tok&15)*8 + ((d>>2)&1)*4
//   v   (element (d,tok)):  off = (d>>4)*1024 + (tok>>4)*256 + ((tok>>3)&1)*128
//                                 + (d&15)*8 + ((tok>>2)&1)*4

// ---------------------------------------------------------------- prep (FULL)
__global__ void prep_full(const float* __restrict__ wqkv, const float* __restrict__ wproj,
                          const float* __restrict__ emb, const int* __restrict__ indices,
                          const float* __restrict__ mask,
                          unsigned short* __restrict__ wqkvP,
                          unsigned short* __restrict__ wprojP,
                          unsigned short* __restrict__ bm2){
    int i = blockIdx.x * 256 + threadIdx.x;
    if (i < 442368){
        int j = i & 7, rest = i >> 3;
        int ln = rest & 63; rest >>= 6;
        int kf = rest % 12, t = rest / 12;
        int k = kf * 32 + (ln >> 4) * 8 + j;
        int col = t * 16 + (ln & 15);
        wqkvP[i] = f2b(wqkv[k * 1152 + col]);
        return;
    }
    i -= 442368;
    if (i < 147456){
        int j = i & 7, rest = i >> 3;
        int ln = rest & 63; rest >>= 6;
        int kf = rest % 12, t = rest / 12;
        int k = kf * 32 + (ln >> 4) * 8 + j;
        int col = t * 16 + (ln & 15);
        wprojP[i] = f2b(wproj[k * 384 + col]);
        return;
    }
    i -= 147456;
    if (i < 64 * 12 * 4096){
        int w = i / 49152, rem = i % 49152;
        int h = rem / 4096, r2 = rem & 4095;
        int col = r2 >> 6, row = r2 & 63;          // col=key, row=query
        int ij = row * 64 + col;
        float v = emb[indices[ij] * 12 + h] + emb[indices[4096 + ij] * 12 + h]
                + mask[w * 4096 + ij];
        bm2[i] = f2b(v);
    }
}

// ---------------------------------------------------------------- K1 (FULL)
// One window per block, EIGHT waves (512 thr). q and k sections FUSED into
// one kf loop: they use identical A-fragments and the same swapped-operand
// MFMA form, so each A ds_read now feeds 6 MFMAs (3 q-tiles + 3 k-tiles).
// Block A-reads drop 1152->768; B loads stay at the minimum (108/wave).
// acc = aq[3][4]+ak[3][4] = 96 VGPRs: NO min-waves launch bound (allocator
// must not clamp below demand -- round-4's spill), unroll 1 caps B-in-flight.
// v: normal orientation, separate loop. Stores: permuted layout, 512B contig NT.
__global__ __launch_bounds__(512) void qkv_gemm(
    const float* __restrict__ x, const unsigned short* __restrict__ wqkvP,
    unsigned short* __restrict__ qg, unsigned short* __restrict__ kg,
    unsigned short* __restrict__ vg)
{
    __shared__ unsigned short As[64 * 384];       // 48 KiB, chunk-swizzled
    const int tid = threadIdx.x, wave = tid >> 6, lane = tid & 63;
    const int lo = lane & 15, hi = lane >> 4;
    const int win = blockIdx.x;
    const int widx = win & 63, wh = widx >> 3, ww = widx & 7, b = win >> 6;

    { // stage A: 64 rows, 8 threads/row, 6 chunks of 8 bf16 each (nt f32 loads)
        const int r = tid >> 3;
        const int ih = r >> 3, iw = r & 7;
        const int gh = (wh * 8 + ih + 4) & 63, gw = (ww * 8 + iw + 4) & 63;
        const float* src = x + ((size_t)(b * 4096 + gh * 64 + gw)) * 384;
        unsigned short* dst = As + r * 384;
        const int sw = r & 7;
        #pragma unroll
        for (int i = 0; i < 6; ++i){
            const int c = (tid & 7) + i * 8;
            f32x4v f0 = __builtin_nontemporal_load(
                reinterpret_cast<const f32x4v*>(src + c * 8));
            f32x4v f1 = __builtin_nontemporal_load(
                reinterpret_cast<const f32x4v*>(src + c * 8 + 4));
            union { bf16x8 v; unsigned short s[8]; } u;
            u.s[0]=f2b(f0[0]); u.s[1]=f2b(f0[1]); u.s[2]=f2b(f0[2]); u.s[3]=f2b(f0[3]);
            u.s[4]=f2b(f1[0]); u.s[5]=f2b(f1[1]); u.s[6]=f2b(f1[2]); u.s[7]=f2b(f1[3]);
            const int cs = (c & ~7) | ((c & 7) ^ sw);
            *reinterpret_cast<bf16x8*>(dst + cs * 8) = u.v;
        }
    }
    __syncthreads();

    const int g0 = wave * 3;                       // first col-tile within section

    // ---------------- fused q+k pass (swapped operands) ----------------
    {
        const unsigned short* bpq = wqkvP + (size_t)g0 * 12 * 512 + lane * 8;
        const unsigned short* bpk = wqkvP + (size_t)(24 + g0) * 12 * 512 + lane * 8;

        f32x4 aq[3][4], ak[3][4];
        #pragma unroll
        for (int wt = 0; wt < 3; ++wt)
            #pragma unroll
            for (int tt = 0; tt < 4; ++tt){ aq[wt][tt] = {0,0,0,0}; ak[wt][tt] = {0,0,0,0}; }

        #pragma unroll 1
        for (int kf = 0; kf < 12; ++kf){
            bf16x8 bq[3], bk[3];
            #pragma unroll
            for (int wt = 0; wt < 3; ++wt){
                bq[wt] = *reinterpret_cast<const bf16x8*>(bpq + (wt * 12 + kf) * 512);
                bk[wt] = *reinterpret_cast<const bf16x8*>(bpk + (wt * 12 + kf) * 512);
            }
            const int c = kf * 4 + hi;
            #pragma unroll
            for (int tt = 0; tt < 4; ++tt){
                const int r = tt * 16 + lo;
                const int cs = (c & ~7) | ((c & 7) ^ (r & 7));
                bf16x8 af = *reinterpret_cast<const bf16x8*>(As + r * 384 + cs * 8);
                #pragma unroll
                for (int wt = 0; wt < 3; ++wt){
                    aq[wt][tt] = MFMA(bq[wt], af, aq[wt][tt], 0, 0, 0);
                    ak[wt][tt] = MFMA(bk[wt], af, ak[wt][tt], 0, 0, 0);
                }
            }
        }

        // epilogues: permuted layout; each (wt,tt) store op = 512B contiguous
        #pragma unroll
        for (int wt = 0; wt < 3; ++wt){
            const int g = g0 + wt;
            const int hloc = g >> 1, db = g & 1;
            const size_t boff = (size_t)(win * 12 + hloc) * 2048
                              + db * 1024 + (hi >> 1) * 128 + lo * 8 + (hi & 1) * 4;
            unsigned short* dq = qg + boff;
            unsigned short* dk = kg + boff;
            #pragma unroll
            for (int tt = 0; tt < 4; ++tt){
                u16x4 uq, uk;
                uq[0] = f2b(aq[wt][tt][0] * SCALE); uq[1] = f2b(aq[wt][tt][1] * SCALE);
                uq[2] = f2b(aq[wt][tt][2] * SCALE); uq[3] = f2b(aq[wt][tt][3] * SCALE);
                uk[0] = f2b(ak[wt][tt][0]); uk[1] = f2b(ak[wt][tt][1]);
                uk[2] = f2b(ak[wt][tt][2]); uk[3] = f2b(ak[wt][tt][3]);
                __builtin_nontemporal_store(uq, reinterpret_cast<u16x4*>(dq + tt * 256));
                __builtin_nontemporal_store(uk, reinterpret_cast<u16x4*>(dk + tt * 256));
            }
        }
    }

    // ---------------- v pass (normal orientation) ----------------
    {
        const unsigned short* bpv = wqkvP + (size_t)(48 + g0) * 12 * 512 + lane * 8;

        f32x4 av[3][4];
        #pragma unroll
        for (int wt = 0; wt < 3; ++wt)
            #pragma unroll
            for (int tt = 0; tt < 4; ++tt) av[wt][tt] = {0,0,0,0};

        #pragma unroll 2
        for (int kf = 0; kf < 12; ++kf){
            bf16x8 bv[3];
            #pragma unroll
            for (int wt = 0; wt < 3; ++wt)
                bv[wt] = *reinterpret_cast<const bf16x8*>(bpv + (wt * 12 + kf) * 512);
            const int c = kf * 4 + hi;
            #pragma unroll
            for (int tt = 0; tt < 4; ++tt){
                const int r = tt * 16 + lo;
                const int cs = (c & ~7) | ((c & 7) ^ (r & 7));
                bf16x8 af = *reinterpret_cast<const bf16x8*>(As + r * 384 + cs * 8);
                #pragma unroll
                for (int wt = 0; wt < 3; ++wt)
                    av[wt][tt] = MFMA(af, bv[wt], av[wt][tt], 0, 0, 0);
            }
        }

        #pragma unroll
        for (int wt = 0; wt < 3; ++wt){
            const int g = g0 + wt;
            const int hloc = g >> 1, db = g & 1;
            unsigned short* dst = vg + (size_t)(win * 12 + hloc) * 2048
                                + db * 1024 + (hi >> 1) * 128 + lo * 8 + (hi & 1) * 4;
            #pragma unroll
            for (int tt = 0; tt < 4; ++tt){
                u16x4 u;
                u[0] = f2b(av[wt][tt][0]); u[1] = f2b(av[wt][tt][1]);
                u[2] = f2b(av[wt][tt][2]); u[3] = f2b(av[wt][tt][3]);
                __builtin_nontemporal_store(u, reinterpret_cast<u16x4*>(dst + tt * 256));
            }
        }
    }
}

// ---------------------------------------------------------------- K2a (FULL)
// Attention only. One (window, 4-head group) per block, one head per wave.
// Fragment loads use the granule-permuted q/k/v layout (see top).
// O written bf16 head-major [pair][tok][32] IN PLACE over qg (normal stores).
__global__ __launch_bounds__(256, 4) void attn_only(
    const unsigned short* __restrict__ qg, const unsigned short* __restrict__ kg,
    const unsigned short* __restrict__ vg, const unsigned short* __restrict__ bm2,
    unsigned short* __restrict__ Og)
{
    __shared__ unsigned short psm_all[4][64 * 64];   // 32 KiB, XOR-swizzled
    __shared__ unsigned short tb_all[4][512];        // 4 KiB transpose bounce
    const int tid = threadIdx.x, wave = tid >> 6, lane = tid & 63;
    const int lo = lane & 15, hi = lane >> 4;
    const int bid = blockIdx.x;
    const int win = bid / 3, e = bid - win * 3;
    const int widx = win & 63;
    const int h = e * 4 + wave;
    const size_t pair = (size_t)(win * 12 + h);
    const unsigned short* qb  = qg + pair * 2048;
    const unsigned short* kbp = kg + pair * 2048;
    const unsigned short* vb  = vg + pair * 2048;
    const unsigned short* bmb = bm2 + (size_t)(widx * 12 + h) * 4096;
    unsigned short* psm = psm_all[wave];
    const int fbase = (hi >> 1) * 1024 + (hi & 1) * 128 + lo * 8;  // q/k frag base

    bf16x8 kf[4];
    #pragma unroll
    for (int ct = 0; ct < 4; ++ct)
        kf[ct] = *reinterpret_cast<const bf16x8*>(kbp + fbase + ct * 256);

    #pragma unroll
    for (int rh = 0; rh < 2; ++rh){
        f32x4 s[2][4];
        __builtin_amdgcn_s_setprio(1);
        #pragma unroll
        for (int rt2 = 0; rt2 < 2; ++rt2){
            bf16x8 qf = *reinterpret_cast<const bf16x8*>(
                qb + fbase + (rh * 2 + rt2) * 256);
            #pragma unroll
            for (int ct = 0; ct < 4; ++ct){
                f32x4 z = {0,0,0,0};
                s[rt2][ct] = MFMA(qf, kf[ct], z, 0, 0, 0);
            }
        }
        __builtin_amdgcn_s_setprio(0);
        #pragma unroll
        for (int rt2 = 0; rt2 < 2; ++rt2)
            #pragma unroll
            for (int ct = 0; ct < 4; ++ct){
                ushort4 bv = *reinterpret_cast<const ushort4*>(
                    bmb + (ct * 16 + lo) * 64 + (rh * 2 + rt2) * 16 + hi * 4);
                s[rt2][ct][0] += b2f(bv.x);
                s[rt2][ct][1] += b2f(bv.y);
                s[rt2][ct][2] += b2f(bv.z);
                s[rt2][ct][3] += b2f(bv.w);
            }
        #pragma unroll
        for (int rt2 = 0; rt2 < 2; ++rt2)
            #pragma unroll
            for (int r4 = 0; r4 < 4; ++r4){
                float mx = fmaxf(fmaxf(s[rt2][0][r4], s[rt2][1][r4]),
                                 fmaxf(s[rt2][2][r4], s[rt2][3][r4]));
                mx = fmaxf(mx, __shfl_xor(mx, 1, 64));
                mx = fmaxf(mx, __shfl_xor(mx, 2, 64));
                mx = fmaxf(mx, __shfl_xor(mx, 4, 64));
                mx = fmaxf(mx, __shfl_xor(mx, 8, 64));
                float e0 = __expf(s[rt2][0][r4] - mx), e1 = __expf(s[rt2][1][r4] - mx);
                float e2 = __expf(s[rt2][2][r4] - mx), e3 = __expf(s[rt2][3][r4] - mx);
                float sm = e0 + e1 + e2 + e3;
                sm += __shfl_xor(sm, 1, 64);
                sm += __shfl_xor(sm, 2, 64);
                sm += __shfl_xor(sm, 4, 64);
                sm += __shfl_xor(sm, 8, 64);
                const float inv = 1.0f / sm;
                const int row = (rh * 2 + rt2) * 16 + hi * 4 + r4;
                const int rsw = row & 7;
                #pragma unroll
                for (int ct = 0; ct < 4; ++ct){
                    const int c = ct * 2 + (lo >> 3);
                    const float ev = (ct == 0 ? e0 : ct == 1 ? e1 : ct == 2 ? e2 : e3);
                    psm[row * 64 + (c ^ rsw) * 8 + (lo & 7)] = f2b(ev * inv);
                }
            }
    }
    asm volatile("" ::: "memory");

    f32x4 o[4][2];
    #pragma unroll
    for (int rt = 0; rt < 4; ++rt){ o[rt][0] = {0,0,0,0}; o[rt][1] = {0,0,0,0}; }
    #pragma unroll
    for (int ks = 0; ks < 2; ++ks){
        bf16x8 vf[2];
        #pragma unroll
        for (int ct2 = 0; ct2 < 2; ++ct2)
            vf[ct2] = *reinterpret_cast<const bf16x8*>(
                vb + ct2 * 1024 + (ks * 2 + (hi >> 1)) * 256 + (hi & 1) * 128 + lo * 8);
        __builtin_amdgcn_s_setprio(1);
        #pragma unroll
        for (int rt = 0; rt < 4; ++rt){
            const int row = rt * 16 + lo;
            const int c = ks * 4 + hi;
            bf16x8 pa = *reinterpret_cast<const bf16x8*>(
                psm + row * 64 + (c ^ (row & 7)) * 8);
            o[rt][0] = MFMA(pa, vf[0], o[rt][0], 0, 0, 0);
            o[rt][1] = MFMA(pa, vf[1], o[rt][1], 0, 0, 0);
        }
        __builtin_amdgcn_s_setprio(0);
    }

    // O epilogue: C-layout -> [tok][32] via LDS bounce -> 1KB coalesced store.
    // NORMAL store (cached): proj_only reads this back immediately.
    unsigned short* tb = tb_all[wave];
    #pragma unroll
    for (int rt = 0; rt < 4; ++rt){
        asm volatile("" ::: "memory");
        #pragma unroll
        for (int ct2 = 0; ct2 < 2; ++ct2)
            #pragma unroll
            for (int r4 = 0; r4 < 4; ++r4)
                tb[(hi * 4 + r4) * 32 + ct2 * 16 + lo] = f2b(o[rt][ct2][r4]);
        asm volatile("" ::: "memory");
        u16x8 v = *reinterpret_cast<const u16x8*>(tb + (lane >> 2) * 32 + (lane & 3) * 8);
        *reinterpret_cast<u16x8*>(
            Og + pair * 2048 + rt * 512 + (lane >> 2) * 32 + (lane & 3) * 8) = v;
        asm volatile("" ::: "memory");
    }
}

// ---------------------------------------------------------------- K2b (FULL)
// Proj GEMM. HALF-window per block (32 tokens): LDS 24.5K. Stage O (head-major
// bf16, L2-hot) into swizzled As; packed-B GEMM; epilogue bounces f32 through
// LDS so stores are FULL-LINE nontemporal row writes.
__global__ __launch_bounds__(256, 4) void proj_only(
    const unsigned short* __restrict__ Og, const unsigned short* __restrict__ wprojP,
    const float* __restrict__ bproj, float* __restrict__ out)
{
    __shared__ __attribute__((aligned(16))) unsigned char smem[25088];
    unsigned short* As = reinterpret_cast<unsigned short*>(smem);  // 32x384 bf16 swz
    float* Asf = reinterpret_cast<float*>(smem);                   // 16x392 f32 bounce
    const int tid = threadIdx.x, wave = tid >> 6, lane = tid & 63;
    const int lo = lane & 15, hi = lane >> 4;
    const int blk = blockIdx.x;
    const int win = blk >> 1, half = blk & 1;
    const int widx = win & 63, wh = widx >> 3, ww = widx & 7, b = win >> 6;

    { // stage 32 tokens x 384 cols; col chunk c -> head c>>2, sub-chunk c&3
        const int r = tid >> 3;              // local row 0..31
        const int c0 = tid & 7;
        const int tokg = half * 32 + r;
        #pragma unroll
        for (int i = 0; i < 6; ++i){
            const int c = c0 + i * 8;        // chunk 0..47
            const int h = c >> 2;
            bf16x8 v = *reinterpret_cast<const bf16x8*>(
                Og + (size_t)(win * 12 + h) * 2048 + tokg * 32 + (c & 3) * 8);
            const int cs = (c & ~7) | ((c & 7) ^ (r & 7));
            *reinterpret_cast<bf16x8*>(As + r * 384 + cs * 8) = v;
        }
    }
    __syncthreads();

    // GEMM: wave owns 96 output cols (6 tiles); 2 row-tiles (32 tokens)
    f32x4 acc[2][6];
    #pragma unroll
    for (int rt = 0; rt < 2; ++rt)
        #pragma unroll
        for (int ct = 0; ct < 6; ++ct) acc[rt][ct] = {0,0,0,0};
    #pragma unroll
    for (int kf = 0; kf < 12; ++kf){
        bf16x8 bfr[6];
        #pragma unroll
        for (int ct = 0; ct < 6; ++ct){
            const int t = wave * 6 + ct;
            bfr[ct] = *reinterpret_cast<const bf16x8*>(
                wprojP + (size_t)(t * 12 + kf) * 512 + lane * 8);
        }
        const int c = kf * 4 + hi;
        #pragma unroll
        for (int rt = 0; rt < 2; ++rt){
            const int r = rt * 16 + lo;
            const int cs = (c & ~7) | ((c & 7) ^ (r & 7));
            bf16x8 af = *reinterpret_cast<const bf16x8*>(As + r * 384 + cs * 8);
            #pragma unroll
            for (int ct = 0; ct < 6; ++ct)
                acc[rt][ct] = MFMA(af, bfr[ct], acc[rt][ct], 0, 0, 0);
        }
    }

    // epilogue: two 16-token rounds through f32 LDS -> full-row nt stores
    #pragma unroll
    for (int p = 0; p < 2; ++p){
        __syncthreads();
        #pragma unroll
        for (int ct = 0; ct < 6; ++ct){
            const int col = wave * 96 + ct * 16 + lo;
            const float bv = bproj[col];
            #pragma unroll
            for (int r4 = 0; r4 < 4; ++r4)
                Asf[(hi * 4 + r4) * 392 + col] = acc[p][ct][r4] + bv;
        }
        __syncthreads();
        const int row = tid >> 4, tcol = tid & 15;
        const int tok = half * 32 + p * 16 + row;
        const int ih = tok >> 3, iw = tok & 7;
        const int gh = (wh * 8 + ih + 4) & 63, gw = (ww * 8 + iw + 4) & 63;
        float* orow = out + ((size_t)(b * 4096 + gh * 64 + gw)) * 384;
        #pragma unroll
        for (int j = 0; j < 6; ++j){
            f32x4 v = *reinterpret_cast<const f32x4*>(Asf + row * 392 + j * 64 + tcol * 4);
            __builtin_nontemporal_store(v, reinterpret_cast<f32x4*>(orow + j * 64 + tcol * 4));
        }
    }
}

// ---------------------------------------------------------------- prep (MID/LOW)
__global__ void transpose_weights(const float* __restrict__ wqkv,
                                  const float* __restrict__ wproj,
                                  unsigned short* __restrict__ wqkvT,
                                  unsigned short* __restrict__ wprojT){
    int i = blockIdx.x * 256 + threadIdx.x;
    if (i < 1152 * 384){ int j = i / 384, k = i % 384; wqkvT[i] = f2b(wqkv[k * 1152 + j]); }
    i -= 1152 * 384;
    if (i >= 0 && i < 384 * 384){ int j = i / 384, k = i % 384; wprojT[i] = f2b(wproj[k * 384 + j]); }
}

// ---------------------------------------------------------------- MID fused (no proj)
__global__ __launch_bounds__(256) void fused_noproj(
    const float* __restrict__ x, const float* __restrict__ emb,
    const int* __restrict__ indices, const float* __restrict__ mask,
    const unsigned short* __restrict__ wqkvT, unsigned short* __restrict__ Og)
{
    __shared__ unsigned short smem[37120];
    unsigned short* xw = smem;
    unsigned short* qT = smem + 25088;
    unsigned short* kT = smem + 27648;
    unsigned short* vT = smem + 30208;
    unsigned short* pT = smem + 32512;

    const int tid = threadIdx.x, wave = tid >> 6, lane = tid & 63;
    const int lo = lane & 15, hi = lane >> 4;
    const int blk = blockIdx.x, b = blk >> 6, widx = blk & 63;
    const int wh = widx >> 3, wwi = widx & 7;

    {
        const int n = tid >> 2, qp = tid & 3;
        const int ih = n >> 3, iw = n & 7;
        const int gh = ((wh * 8 + ih) + 4) & 63, gw = ((wwi * 8 + iw) + 4) & 63;
        const size_t src = ((size_t)b * 4096 + gh * 64 + gw) * 384 + qp * 96;
        const float4* gp = reinterpret_cast<const float4*>(x + src);
        unsigned short* dst = xw + n * 392 + qp * 96;
        #pragma unroll
        for (int i = 0; i < 24; ++i){
            float4 f = gp[i];
            ushort4 u;
            u.x = f2b(f.x); u.y = f2b(f.y); u.z = f2b(f.z); u.w = f2b(f.w);
            *reinterpret_cast<ushort4*>(dst + i * 4) = u;
        }
    }
    __syncthreads();

    for (int h = 0; h < NHEADS; ++h){
        #pragma unroll
        for (int j = 0; j < 6; ++j){
            const int t = wave * 6 + j;
            const int m = t >> 3, tt = t & 7;
            const int tr = tt >> 1, tc = tt & 1;
            const int col = m * 384 + h * 32 + tc * 16 + lo;
            f32x4 acc = {0.f, 0.f, 0.f, 0.f};
            #pragma unroll
            for (int kb = 0; kb < 12; ++kb){
                bf16x8 a = *reinterpret_cast<const bf16x8*>(xw + (tr * 16 + lo) * 392 + kb * 32 + hi * 8);
                bf16x8 bb = *reinterpret_cast<const bf16x8*>(wqkvT + (size_t)col * 384 + kb * 32 + hi * 8);
                acc = MFMA(a, bb, acc, 0, 0, 0);
            }
            #pragma unroll
            for (int r = 0; r < 4; ++r){
                const int token = tr * 16 + hi * 4 + r;
                const int d = tc * 16 + lo;
                if (m == 0)      qT[token * 40 + d] = f2b(acc[r] * SCALE);
                else if (m == 1) kT[token * 40 + d] = f2b(acc[r]);
                else             vT[d * 72 + token] = f2b(acc[r]);
            }
        }
        __syncthreads();
        {
            const int mi = wave;
            bf16x8 qf = *reinterpret_cast<const bf16x8*>(qT + (mi * 16 + lo) * 40 + hi * 8);
            f32x4 s[4];
            #pragma unroll
            for (int ni = 0; ni < 4; ++ni){
                bf16x8 kfr = *reinterpret_cast<const bf16x8*>(kT + (ni * 16 + lo) * 40 + hi * 8);
                f32x4 z = {0.f, 0.f, 0.f, 0.f};
                s[ni] = MFMA(qf, kfr, z, 0, 0, 0);
            }
            #pragma unroll
            for (int ni = 0; ni < 4; ++ni){
                const int kk = ni * 16 + lo;
                #pragma unroll
                for (int r = 0; r < 4; ++r){
                    const int qq = mi * 16 + hi * 4 + r;
                    const int ij = qq * 64 + kk;
                    s[ni][r] += emb[indices[ij] * 12 + h] + emb[indices[4096 + ij] * 12 + h]
                              + mask[widx * 4096 + ij];
                }
            }
            #pragma unroll
            for (int r = 0; r < 4; ++r){
                float mx = fmaxf(fmaxf(s[0][r], s[1][r]), fmaxf(s[2][r], s[3][r]));
                mx = fmaxf(mx, __shfl_xor(mx, 1, 64));
                mx = fmaxf(mx, __shfl_xor(mx, 2, 64));
                mx = fmaxf(mx, __shfl_xor(mx, 4, 64));
                mx = fmaxf(mx, __shfl_xor(mx, 8, 64));
                float e0 = __expf(s[0][r] - mx), e1 = __expf(s[1][r] - mx);
                float e2 = __expf(s[2][r] - mx), e3 = __expf(s[3][r] - mx);
                float sm = e0 + e1 + e2 + e3;
                sm += __shfl_xor(sm, 1, 64);
                sm += __shfl_xor(sm, 2, 64);
                sm += __shfl_xor(sm, 4, 64);
                sm += __shfl_xor(sm, 8, 64);
                float inv = 1.0f / sm;
                const int qq = mi * 16 + hi * 4 + r;
                pT[qq * 72 +  0 + lo] = f2b(e0 * inv);
                pT[qq * 72 + 16 + lo] = f2b(e1 * inv);
                pT[qq * 72 + 32 + lo] = f2b(e2 * inv);
                pT[qq * 72 + 48 + lo] = f2b(e3 * inv);
            }
        }
        __syncthreads();
        {
            const int tr = wave;
            #pragma unroll
            for (int tc = 0; tc < 2; ++tc){
                f32x4 acc = {0.f, 0.f, 0.f, 0.f};
                #pragma unroll
                for (int st = 0; st < 2; ++st){
                    bf16x8 a = *reinterpret_cast<const bf16x8*>(pT + (tr * 16 + lo) * 72 + st * 32 + hi * 8);
                    bf16x8 bb = *reinterpret_cast<const bf16x8*>(vT + (tc * 16 + lo) * 72 + st * 32 + hi * 8);
                    acc = MFMA(a, bb, acc, 0, 0, 0);
                }
                #pragma unroll
                for (int r = 0; r < 4; ++r){
                    const int token = tr * 16 + hi * 4 + r;
                    Og[((size_t)blk * 64 + token) * 384 + h * 32 + tc * 16 + lo] = f2b(acc[r]);
                }
            }
        }
        __syncthreads();
    }
}

// ---------------------------------------------------------------- MID proj
__global__ __launch_bounds__(256) void proj_gemm_T(
    const unsigned short* __restrict__ Og, const unsigned short* __restrict__ wprojT,
    const float* __restrict__ bproj, float* __restrict__ out)
{
    __shared__ unsigned short As[64 * 384];
    const int tid = threadIdx.x, wave = tid >> 6, lane = tid & 63;
    const int lo = lane & 15, hi = lane >> 4;
    const int win = blockIdx.x;
    const int widx = win & 63, wh = widx >> 3, ww = widx & 7, b = win >> 6;

    {
        const int r = tid >> 2;
        const unsigned short* src = Og + ((size_t)win * 64 + r) * 384;
        const int sw = r & 7;
        #pragma unroll
        for (int i = 0; i < 12; ++i){
            const int c = (tid & 3) + i * 4;
            bf16x8 v = *reinterpret_cast<const bf16x8*>(src + c * 8);
            const int cs = (c & ~7) | ((c & 7) ^ sw);
            *reinterpret_cast<bf16x8*>(As + r * 384 + cs * 8) = v;
        }
    }
    __syncthreads();

    #pragma unroll 1
    for (int nc = 0; nc < 3; ++nc){
        f32x4 acc[4][2];
        #pragma unroll
        for (int rt = 0; rt < 4; ++rt){ acc[rt][0] = {0,0,0,0}; acc[rt][1] = {0,0,0,0}; }
        #pragma unroll
        for (int kb = 0; kb < 6; ++kb){
            bf16x8 bf[2][2];
            #pragma unroll
            for (int ct = 0; ct < 2; ++ct)
                #pragma unroll
                for (int ks = 0; ks < 2; ++ks){
                    const int col = nc * 128 + wave * 32 + ct * 16 + lo;
                    bf[ct][ks] = *reinterpret_cast<const bf16x8*>(
                        wprojT + (size_t)col * 384 + kb * 64 + ks * 32 + hi * 8);
                }
            #pragma unroll
            for (int ks = 0; ks < 2; ++ks)
                #pragma unroll
                for (int rt = 0; rt < 4; ++rt){
                    const int r = rt * 16 + lo;
                    const int c = kb * 8 + ks * 4 + hi;
                    const int cs = (c & ~7) | ((c & 7) ^ (r & 7));
                    bf16x8 af = *reinterpret_cast<const bf16x8*>(As + r * 384 + cs * 8);
                    acc[rt][0] = MFMA(af, bf[0][ks], acc[rt][0], 0, 0, 0);
                    acc[rt][1] = MFMA(af, bf[1][ks], acc[rt][1], 0, 0, 0);
                }
        }
        #pragma unroll
        for (int rt = 0; rt < 4; ++rt)
            #pragma unroll
            for (int ct = 0; ct < 2; ++ct){
                const int col = nc * 128 + wave * 32 + ct * 16 + lo;
                const float bv = bproj[col];
                #pragma unroll
                for (int r4 = 0; r4 < 4; ++r4){
                    const int tok = rt * 16 + hi * 4 + r4;
                    const int ih = tok >> 3, iw = tok & 7;
                    const int gh = (wh * 8 + ih + 4) & 63, gw = (ww * 8 + iw + 4) & 63;
                    out[((size_t)(b * 4096 + gh * 64 + gw)) * 384 + col] =
                        acc[rt][ct][r4] + bv;
                }
            }
    }
}

// ---------------------------------------------------------------- LOW fallback
static __device__ __forceinline__ bf16x8 load_bT(const unsigned short* __restrict__ WT,
                                                 const float* __restrict__ Worig,
                                                 int useT, int col, int k0, int ldOrig){
    if (useT){
        return *reinterpret_cast<const bf16x8*>(WT + (size_t)col * 384 + k0);
    } else {
        union { bf16x8 v; unsigned short s[8]; } u;
        #pragma unroll
        for (int i = 0; i < 8; ++i) u.s[i] = f2b(Worig[(size_t)(k0 + i) * ldOrig + col]);
        return u.v;
    }
}

__global__ __launch_bounds__(256) void swin_attn_kernel(
    const float* __restrict__ x, const float* __restrict__ wqkv,
    const float* __restrict__ wproj, const float* __restrict__ bproj,
    const float* __restrict__ emb, const int* __restrict__ indices,
    const float* __restrict__ mask, const unsigned short* __restrict__ wqkvT,
    const unsigned short* __restrict__ wprojT, int useT, float* __restrict__ out)
{
    __shared__ unsigned short smem[62208];
    unsigned short* xw = smem;
    unsigned short* O  = smem + 25088;
    unsigned short* qT = smem + 50176;
    unsigned short* kT = smem + 52736;
    unsigned short* vT = smem + 55296;
    unsigned short* pT = smem + 57600;

    const int tid = threadIdx.x, wave = tid >> 6, lane = tid & 63;
    const int lo = lane & 15, hi = lane >> 4;
    const int blk = blockIdx.x, b = blk >> 6, widx = blk & 63;
    const int wh = widx >> 3, wwi = widx & 7;

    {
        const int n = tid >> 2, qp = tid & 3;
        const int ih = n >> 3, iw = n & 7;
        const int gh = ((wh * 8 + ih) + 4) & 63, gw = ((wwi * 8 + iw) + 4) & 63;
        const size_t src = ((size_t)b * 4096 + gh * 64 + gw) * 384 + qp * 96;
        const float4* gp = reinterpret_cast<const float4*>(x + src);
        unsigned short* dst = xw + n * 392 + qp * 96;
        #pragma unroll
        for (int i = 0; i < 24; ++i){
            float4 f = gp[i];
            ushort4 u;
            u.x = f2b(f.x); u.y = f2b(f.y); u.z = f2b(f.z); u.w = f2b(f.w);
            *reinterpret_cast<ushort4*>(dst + i * 4) = u;
        }
    }
    __syncthreads();

    for (int h = 0; h < NHEADS; ++h){
        #pragma unroll
        for (int j = 0; j < 6; ++j){
            const int t = wave * 6 + j;
            const int m = t >> 3, tt = t & 7;
            const int tr = tt >> 1, tc = tt & 1;
            const int col = m * 384 + h * 32 + tc * 16 + lo;
            f32x4 acc = {0.f, 0.f, 0.f, 0.f};
            #pragma unroll
            for (int kb = 0; kb < 12; ++kb){
                bf16x8 a = *reinterpret_cast<const bf16x8*>(xw + (tr * 16 + lo) * 392 + kb * 32 + hi * 8);
                bf16x8 bb = load_bT(wqkvT, wqkv, useT, col, kb * 32 + hi * 8, 1152);
                acc = MFMA(a, bb, acc, 0, 0, 0);
            }
            #pragma unroll
            for (int r = 0; r < 4; ++r){
                const int token = tr * 16 + hi * 4 + r;
                const int d = tc * 16 + lo;
                if (m == 0)      qT[token * 40 + d] = f2b(acc[r] * SCALE);
                else if (m == 1) kT[token * 40 + d] = f2b(acc[r]);
                else             vT[d * 72 + token] = f2b(acc[r]);
            }
        }
        __syncthreads();
        {
            const int mi = wave;
            bf16x8 qf = *reinterpret_cast<const bf16x8*>(qT + (mi * 16 + lo) * 40 + hi * 8);
            f32x4 s[4];
            #pragma unroll
            for (int ni = 0; ni < 4; ++ni){
                bf16x8 kfr = *reinterpret_cast<const bf16x8*>(kT + (ni * 16 + lo) * 40 + hi * 8);
                f32x4 z = {0.f, 0.f, 0.f, 0.f};
                s[ni] = MFMA(qf, kfr, z, 0, 0, 0);
            }
            #pragma unroll
            for (int ni = 0; ni < 4; ++ni){
                const int kk = ni * 16 + lo;
                #pragma unroll
                for (int r = 0; r < 4; ++r){
                    const int qq = mi * 16 + hi * 4 + r;
                    const int ij = qq * 64 + kk;
                    s[ni][r] += emb[indices[ij] * 12 + h] + emb[indices[4096 + ij] * 12 + h]
                              + mask[widx * 4096 + ij];
                }
            }
            #pragma unroll
            for (int r = 0; r < 4; ++r){
                float mx = fmaxf(fmaxf(s[0][r], s[1][r]), fmaxf(s[2][r], s[3][r]));
                mx = fmaxf(mx, __shfl_xor(mx, 1, 64));
                mx = fmaxf(mx, __shfl_xor(mx, 2, 64));
                mx = fmaxf(mx, __shfl_xor(mx, 4, 64));
                mx = fmaxf(mx, __shfl_xor(mx, 8, 64));
                float e0 = __expf(s[0][r] - mx), e1 = __expf(s[1][r] - mx);
                float e2 = __expf(s[2][r] - mx), e3 = __expf(s[3][r] - mx);
                float sm = e0 + e1 + e2 + e3;
                sm += __shfl_xor(sm, 1, 64);
                sm += __shfl_xor(sm, 2, 64);
                sm += __shfl_xor(sm, 4, 64);
                sm += __shfl_xor(sm, 8, 64);
                float inv = 1.0f / sm;
                const int qq = mi * 16 + hi * 4 + r;
                pT[qq * 72 +  0 + lo] = f2b(e0 * inv);
                pT[qq * 72 + 16 + lo] = f2b(e1 * inv);
                pT[qq * 72 + 32 + lo] = f2b(e2 * inv);
                pT[qq * 72 + 48 + lo] = f2b(e3 * inv);
            }
        }
        __syncthreads();
        {
            const int tr = wave;
            #pragma unroll
            for (int tc = 0; tc < 2; ++tc){
                f32x4 acc = {0.f, 0.f, 0.f, 0.f};
                #pragma unroll
                for (int st = 0; st < 2; ++st){
                    bf16x8 a = *reinterpret_cast<const bf16x8*>(pT + (tr * 16 + lo) * 72 + st * 32 + hi * 8);
                    bf16x8 bb = *reinterpret_cast<const bf16x8*>(vT + (tc * 16 + lo) * 72 + st * 32 + hi * 8);
                    acc = MFMA(a, bb, acc, 0, 0, 0);
                }
                #pragma unroll
                for (int r = 0; r < 4; ++r){
                    const int token = tr * 16 + hi * 4 + r;
                    O[token * 392 + h * 32 + tc * 16 + lo] = f2b(acc[r]);
                }
            }
        }
        __syncthreads();
    }
    {
        const int tr = wave;
        bf16x8 afr[12];
        #pragma unroll
        for (int kb = 0; kb < 12; ++kb)
            afr[kb] = *reinterpret_cast<const bf16x8*>(O + (tr * 16 + lo) * 392 + kb * 32 + hi * 8);
        for (int tc = 0; tc < 24; ++tc){
            const int col = tc * 16 + lo;
            f32x4 acc = {0.f, 0.f, 0.f, 0.f};
            #pragma unroll
            for (int kb = 0; kb < 12; ++kb){
                bf16x8 bb = load_bT(wprojT, wproj, useT, col, kb * 32 + hi * 8, 384);
                acc = MFMA(afr[kb], bb, acc, 0, 0, 0);
            }
            const float bv = bproj[col];
            #pragma unroll
            for (int r = 0; r < 4; ++r){
                const int token = tr * 16 + hi * 4 + r;
                const int ih = token >> 3, iw = token & 7;
                const int gh = ((wh * 8 + ih) + 4) & 63, gw = ((wwi * 8 + iw) + 4) & 63;
                out[((size_t)b * 4096 + gh * 64 + gw) * 384 + col] = acc[r] + bv;
            }
        }
    }
}

// ---------------------------------------------------------------- launch
extern "C" void kernel_launch(void* const* d_in, const int* in_sizes, int n_in,
                              void* d_out, int out_size, void* d_ws, size_t ws_size,
                              hipStream_t stream){
    const float* x     = (const float*)d_in[0];
    const float* wqkv  = (const float*)d_in[1];
    const float* wproj = (const float*)d_in[2];
    const float* bproj = (const float*)d_in[3];
    const float* emb   = (const float*)d_in[4];
    const int*   idx   = (const int*)d_in[5];
    const float* mask  = (const float*)d_in[6];
    float* out = (float*)d_out;

    const int B = in_sizes[0] / (4096 * 384);
    const int NWIN = B * 64;

    unsigned short* ws = (unsigned short*)d_ws;
    const size_t W1 = (size_t)1152 * 384;           // wqkvP elems
    const size_t W2 = (size_t)384 * 384;            // wprojP elems
    const size_t BM = (size_t)64 * 12 * 4096;       // bm2 elems
    const size_t QE = (size_t)NWIN * 12 * 64 * 32;  // q/k/v elems each
    const size_t full_need = (W1 + W2 + BM + 3 * QE) * 2;
    const size_t mid_need  = (W1 + W2 + QE) * 2;
    const size_t low_need  = (W1 + W2) * 2;

    if (d_ws && ws_size >= full_need){
        unsigned short* wqkvP  = ws;
        unsigned short* wprojP = ws + W1;
        unsigned short* bm2    = ws + W1 + W2;
        unsigned short* qg     = bm2 + BM;
        unsigned short* kg     = qg + QE;
        unsigned short* vg     = kg + QE;
        prep_full<<<dim3(14592), dim3(256), 0, stream>>>(wqkv, wproj, emb, idx, mask,
                                                         wqkvP, wprojP, bm2);
        qkv_gemm<<<dim3(NWIN), dim3(512), 0, stream>>>(x, wqkvP, qg, kg, vg);
        // O overwrites qg in place (each wave consumes its q before writing O)
        attn_only<<<dim3(NWIN * 3), dim3(256), 0, stream>>>(qg, kg, vg, bm2, qg);
        proj_only<<<dim3(NWIN * 2), dim3(256), 0, stream>>>(qg, wprojP, bproj, out);
    } else if (d_ws && ws_size >= mid_need){
        unsigned short* wqkvT  = ws;
        unsigned short* wprojT = ws + W1;
        unsigned short* Og     = ws + W1 + W2;
        transpose_weights<<<dim3(2304), dim3(256), 0, stream>>>(wqkv, wproj, wqkvT, wprojT);
        fused_noproj<<<dim3(NWIN), dim3(256), 0, stream>>>(x, emb, idx, mask, wqkvT, Og);
        proj_gemm_T<<<dim3(NWIN), dim3(256), 0, stream>>>(Og, wprojT, bproj, out);
    } else {
        unsigned short* wqkvT  = ws;
        unsigned short* wprojT = ws ? ws + W1 : nullptr;
        const int useT = (d_ws != nullptr && ws_size >= low_need) ? 1 : 0;
        if (useT)
            transpose_weights<<<dim3(2304), dim3(256), 0, stream>>>(wqkv, wproj, wqkvT, wprojT);
        swin_attn_kernel<<<dim3(NWIN), dim3(256), 0, stream>>>(
            x, wqkv, wproj, bproj, emb, idx, mask, wqkvT, wprojT, useT, out);
    }
}